// Round 8
// baseline (198.280 us; speedup 1.0000x reference)
//
#include <hip/hip_runtime.h>

// Problem constants (fixed by the reference)
constexpr int CH    = 384;    // channels
constexpr int NPIX  = 1024;   // H*W = 32*32
constexpr int NHEAD = 12;
constexpr int DH    = 32;     // head dim
constexpr int NB    = 16;     // batch
constexpr float SCALE = 0.17677669529663689f;  // 32^-0.5
constexpr float LOG2E = 1.4426950408889634f;

typedef __attribute__((ext_vector_type(8))) short bf16x8;  // 8 bf16 (4 VGPRs)
typedef __attribute__((ext_vector_type(4))) float f32x4;   // MFMA C/D frag

// Fragment-major ("swizzled") operand layout for the LDS-free GEMMs:
// a K-major matrix [R][384] is stored as [R/16][12] blocks of 512 bf16;
// within a block, lane (quad*16+cc) holds row cc, k = quad*8..+7 of the
// 32-wide k-chunk, at offset lane*8.  A fragment load is then
// base + lane*8 -> 1 KB fully coalesced per wave instruction.
// elem (r, ch):  off = ((r>>4)*12 + (ch>>5))*512 + (((ch>>3)&3)*16 + (r&15))*8 + (ch&7)

// pack two fp32 -> two bf16, round-half-up (3 VALU)
__device__ __forceinline__ unsigned pk2(float a, float b) {
  return __builtin_amdgcn_perm(__float_as_uint(b) + 0x8000u,
                               __float_as_uint(a) + 0x8000u, 0x07060302u);
}
// pack two fp32 -> two bf16, TRUNCATE (1 VALU) — P only; bias cancels in P/l.
__device__ __forceinline__ unsigned pk2t(float a, float b) {
  return __builtin_amdgcn_perm(__float_as_uint(b), __float_as_uint(a), 0x07060302u);
}

// 2^x on the VALU (v_exp_f32 computes 2^x natively)
#if __has_builtin(__builtin_amdgcn_exp2f)
#define EXP2F(x) __builtin_amdgcn_exp2f(x)
#else
#define EXP2F(x) exp2f(x)
#endif

// ---------------------------------------------------------------------------
// Fused prep: blocks [0,1536) transpose x [b][c][n] fp32 -> xt swizzled bf16
// (per batch: 64 row-blocks x 12 k-chunks); blocks [1536,2112) convert
// weights to swizzled bf16 (Q rows pre-scaled by SCALE*log2e: base-2 logits).
// ---------------------------------------------------------------------------
__global__ __launch_bounds__(256) void prep_fused(
    const float* __restrict__ x, const float* __restrict__ qw,
    const float* __restrict__ pw, unsigned short* __restrict__ xts,
    unsigned short* __restrict__ wqs, unsigned short* __restrict__ pws) {
  const int bx = blockIdx.x;
  const int tid = threadIdx.x;
  if (bx < 1536) {
    __shared__ float T[64][65];
    const int b = bx / 96, rem = bx - b * 96;
    const int c0 = (rem >> 4) * 64, n0 = (rem & 15) * 64;
    const float* xb = x + ((size_t)b * CH + c0) * NPIX + n0;
    const int rn = (tid & 15) * 4, rc = tid >> 4;
#pragma unroll
    for (int i = 0; i < 4; i++) {
      float4 v = *(const float4*)(xb + (size_t)(rc + i * 16) * NPIX + rn);
      T[rc + i * 16][rn + 0] = v.x;
      T[rc + i * 16][rn + 1] = v.y;
      T[rc + i * 16][rn + 2] = v.z;
      T[rc + i * 16][rn + 3] = v.w;
    }
    __syncthreads();
    const int wc = (tid & 15) * 4;  // channel offset within the 64-wide c tile
    const int ch = c0 + wc;         // 4 consecutive channels, j = ch&7 in {0,4}
    const int kc = ch >> 5, qd = (ch >> 3) & 3, j = ch & 7;
#pragma unroll
    for (int i = 0; i < 4; i++) {
      const int nl = (tid >> 4) + i * 16;       // local pixel row
      const int ng = n0 + nl;
      uint2 p = {pk2(T[wc][nl], T[wc + 1][nl]), pk2(T[wc + 2][nl], T[wc + 3][nl])};
      size_t off = (((size_t)b * 64 + (ng >> 4)) * 12 + kc) * 512 +
                   (qd * 16 + (ng & 15)) * 8 + j;
      *(uint2*)(xts + off) = p;
    }
  } else {
    const int idx = (bx - 1536) * 256 + tid;
    if (idx < 110592) {
      float4 v = ((const float4*)qw)[idx];
      const int o  = (idx * 4) / CH;  // 4 | 384: never crosses a row
      const int ch = (idx * 4) - o * CH;
      const float sc = (o < CH) ? SCALE * LOG2E : 1.0f;
      size_t off = (((size_t)(o >> 4)) * 12 + (ch >> 5)) * 512 +
                   (((ch >> 3) & 3) * 16 + (o & 15)) * 8 + (ch & 7);
      *(uint2*)(wqs + off) =
          (uint2){pk2(v.x * sc, v.y * sc), pk2(v.z * sc, v.w * sc)};
    } else {
      const int jdx = idx - 110592;
      float4 v = ((const float4*)pw)[jdx];
      const int o  = (jdx * 4) / CH;
      const int ch = (jdx * 4) - o * CH;
      size_t off = (((size_t)(o >> 4)) * 12 + (ch >> 5)) * 512 +
                   (((ch >> 3) & 3) * 16 + (o & 15)) * 8 + (ch & 7);
      *(uint2*)(pws + off) = (uint2){pk2(v.x, v.y), pk2(v.z, v.w)};
    }
  }
}

// ---------------------------------------------------------------------------
// QKV GEMM v3: LDS-free, SWIZZLED operands.  Y[o, b*1024+n] = Wq.XT^T.
// Every fragment load is base + lane*8 (1 KB coalesced); 1-iter register
// prefetch; no barriers, no LDS, no waitcnt drains.  Grid x = b*8+ntile
// pins each batch's xt slice to one XCD.  V-blocks swap MFMA operands so
// C rows = consecutive pixels -> vectorized d-major stores.
// ---------------------------------------------------------------------------
__global__ __launch_bounds__(256, 3) void qkv_mfma(
    const unsigned short* __restrict__ xts, const unsigned short* __restrict__ wqs,
    unsigned short* __restrict__ qb, unsigned short* __restrict__ kb,
    unsigned short* __restrict__ vtb) {
  const int bx = blockIdx.x;          // b = bx>>3, ntile = bx&7
  const int b  = bx >> 3;
  const int n0 = (bx & 7) * 128;
  const int m0 = blockIdx.y * 128;    // 0..8
  const int qkv_t = blockIdx.y / 3;   // 0=Q, 1=K, 2=V
  const int tid = threadIdx.x, wave = tid >> 6, lane = tid & 63;
  const int wm = (wave >> 1) * 64, wn = (wave & 1) * 64;
  const int cc = lane & 15, quad = lane >> 4;

  const unsigned short* abase =
      wqs + ((size_t)((m0 + wm) >> 4) * 12) * 512 + lane * 8;
  const unsigned short* bbase =
      xts + (((size_t)b * 64 + ((n0 + wn) >> 4)) * 12) * 512 + lane * 8;

  f32x4 acc[4][4];
#pragma unroll
  for (int i = 0; i < 4; i++)
#pragma unroll
    for (int j = 0; j < 4; j++) acc[i][j] = (f32x4){0.f, 0.f, 0.f, 0.f};

  bf16x8 af[4], bfr[4];
#pragma unroll
  for (int t = 0; t < 4; t++) af[t] = *(const bf16x8*)(abase + (size_t)(t * 12) * 512);
#pragma unroll
  for (int t = 0; t < 4; t++) bfr[t] = *(const bf16x8*)(bbase + (size_t)(t * 12) * 512);

#pragma unroll 2
  for (int kc = 0; kc < 12; kc++) {
    const int k2 = (kc + 1 < 12) ? kc + 1 : 0;  // wrap: redundant, in-bounds
    bf16x8 naf[4], nbf[4];
#pragma unroll
    for (int t = 0; t < 4; t++)
      naf[t] = *(const bf16x8*)(abase + (size_t)(t * 12 + k2) * 512);
#pragma unroll
    for (int t = 0; t < 4; t++)
      nbf[t] = *(const bf16x8*)(bbase + (size_t)(t * 12 + k2) * 512);

    if (qkv_t < 2) {
#pragma unroll
      for (int i = 0; i < 4; i++)
#pragma unroll
        for (int j = 0; j < 4; j++)
          acc[i][j] = __builtin_amdgcn_mfma_f32_16x16x32_bf16(af[i], bfr[j], acc[i][j], 0, 0, 0);
    } else {  // V: swap -> C rows = pixels, cols = weight-o
#pragma unroll
      for (int i = 0; i < 4; i++)
#pragma unroll
        for (int j = 0; j < 4; j++)
          acc[i][j] = __builtin_amdgcn_mfma_f32_16x16x32_bf16(bfr[i], af[j], acc[i][j], 0, 0, 0);
    }
#pragma unroll
    for (int t = 0; t < 4; t++) { af[t] = naf[t]; bfr[t] = nbf[t]; }
  }

  const int obase = m0 - qkv_t * CH;  // 0/128/256 within the Q/K/V segment
  if (qkv_t < 2) {
    unsigned short* dst0 = (qkv_t == 0) ? qb : kb;
#pragma unroll
    for (int mt = 0; mt < 4; mt++) {
      const int o = obase + wm + mt * 16 + quad * 4;  // [0,384)
      const int h = o >> 5, d0 = o & 31;
      unsigned short* drow = dst0 + ((size_t)(b * NHEAD + h) * NPIX) * DH + d0;
#pragma unroll
      for (int nt = 0; nt < 4; nt++) {
        const int n = n0 + wn + nt * 16 + cc;
        uint2 p = {pk2(acc[mt][nt][0], acc[mt][nt][1]),
                   pk2(acc[mt][nt][2], acc[mt][nt][3])};
        *(uint2*)(drow + (size_t)n * DH) = p;
      }
    }
  } else {
#pragma unroll
    for (int i = 0; i < 4; i++) {
      const int nbase = n0 + wn + i * 16 + quad * 4;
#pragma unroll
      for (int j = 0; j < 4; j++) {
        const int od = obase + wm + j * 16 + cc;
        const int h = od >> 5, dd = od & 31;
        unsigned short* vrow = vtb + ((size_t)(b * NHEAD + h) * DH + dd) * NPIX;
        *(uint2*)(vrow + nbase) = (uint2){pk2(acc[i][j][0], acc[i][j][1]),
                                          pk2(acc[i][j][2], acc[i][j][3])};
      }
    }
  }
}

// ---------------------------------------------------------------------------
// attn iteration body (R3's proven per-32-key pattern).  All register state
// passed by reference with NAMED variables — no runtime-indexed arrays
// anywhere (R7 lesson: Kb0[it&1] went to scratch: WRITE_SIZE 12->60 MB).
// Consumes K-tile (cK0,cK1) and V(t-1) (Vr0,Vr1); refills cK*/cV* with
// tile kt2 = t+2 (depth-2 pipeline: ~2 full bodies between issue and use).
// ---------------------------------------------------------------------------
__device__ __forceinline__ void attn_body(
    const unsigned short* __restrict__ kbase,
    const unsigned short* __restrict__ vrow0,
    const unsigned short* __restrict__ vrow1,
    int c, int Q0, int kt2,
    const bf16x8 (&Bq)[4], bf16x8 (&Bp)[4],
    unsigned short* const (&prow)[4],
    f32x4 (&o0)[4], f32x4 (&o1)[4], f32x4 (&ls)[4],
    bf16x8& cK0, bf16x8& cK1, bf16x8& cV0, bf16x8& cV1,
    bf16x8& Vr0, bf16x8& Vr1) {
  const f32x4 zero = {0.f, 0.f, 0.f, 0.f};
  const short ONE = (short)0x3F80;  // bf16 1.0
  const bf16x8 ones = {ONE, ONE, ONE, ONE, ONE, ONE, ONE, ONE};

  f32x4 s0[4], s1[4];
#pragma unroll
  for (int g = 0; g < 4; g++) {
    s0[g] = __builtin_amdgcn_mfma_f32_16x16x32_bf16(cK0, Bq[g], zero, 0, 0, 0);
    s1[g] = __builtin_amdgcn_mfma_f32_16x16x32_bf16(cK1, Bq[g], zero, 0, 0, 0);
  }
#pragma unroll
  for (int g = 0; g < 4; g++) {
    o0[g] = __builtin_amdgcn_mfma_f32_16x16x32_bf16(Vr0, Bp[g], o0[g], 0, 0, 0);
    o1[g] = __builtin_amdgcn_mfma_f32_16x16x32_bf16(Vr1, Bp[g], o1[g], 0, 0, 0);
    ls[g] = __builtin_amdgcn_mfma_f32_16x16x32_bf16(ones, Bp[g], ls[g], 0, 0, 0);
  }
  // save V(t) for next body's PV skew, then refill this slot with tile t+2
  bf16x8 sV0 = cV0, sV1 = cV1;
  cK0 = *(const bf16x8*)(kbase + (size_t)(kt2 + c) * DH + Q0 * 8);
  cK1 = *(const bf16x8*)(kbase + (size_t)(kt2 + 16 + c) * DH + Q0 * 8);
  cV0 = *(const bf16x8*)(vrow0 + kt2 + Q0 * 8);
  cV1 = *(const bf16x8*)(vrow1 + kt2 + Q0 * 8);
#pragma unroll
  for (int g = 0; g < 4; g++) {
    float p0[4], p1[4];
#pragma unroll
    for (int r = 0; r < 4; r++) p0[r] = EXP2F(s0[g][r]);
#pragma unroll
    for (int r = 0; r < 4; r++) p1[r] = EXP2F(s1[g][r]);
    *(uint2*)(prow[g] + 4 * Q0)      = (uint2){pk2t(p0[0], p0[1]), pk2t(p0[2], p0[3])};
    *(uint2*)(prow[g] + 16 + 4 * Q0) = (uint2){pk2t(p1[0], p1[1]), pk2t(p1[2], p1[3])};
  }
#pragma unroll
  for (int g = 0; g < 4; g++) Bp[g] = *(const bf16x8*)(prow[g] + 8 * Q0);
  Vr0 = sV0; Vr1 = sV1;
}

// ---------------------------------------------------------------------------
// MFMA attention v8: R3's structure (g=4, KT=32, key-split x2, PSTR=36, LDS
// P roundtrip, (256,3), grid (192,8)) + depth-2 K/V register pipeline with
// HAND-UNROLLED x2 loop and individually named slot registers (KA*/KB*) —
// the spill-proof version of R7's single change.  A K/V load now has two
// full iteration bodies (~6500 wave-cyc) before first use.
// ---------------------------------------------------------------------------
__global__ __launch_bounds__(256, 3) void attn_mfma(
    const unsigned short* __restrict__ qb, const unsigned short* __restrict__ kb,
    const unsigned short* __restrict__ vtb, unsigned short* __restrict__ ao) {
  constexpr int PSTR = 36;  // 72 B rows: 18c mod 32 hits all 16 even residues
  // 18432 B, shared by Pbuf (during the loop) and the combine buffers (after)
  __shared__ __align__(16) unsigned char smem[18432];
  unsigned short (*Pbuf)[4][16][PSTR] =
      reinterpret_cast<unsigned short(*)[4][16][PSTR]>(smem);  // [4][4][16][36]
  f32x4 (*O0b)[4][64] = reinterpret_cast<f32x4(*)[4][64]>(smem);          // [2][4][64]
  f32x4 (*O1b)[4][64] = reinterpret_cast<f32x4(*)[4][64]>(smem + 8192);   // [2][4][64]
  float (*Lb)[4][64]  = reinterpret_cast<float(*)[4][64]>(smem + 16384);  // [2][4][64]

  const int bh   = blockIdx.x;  // 0..191  (x-major -> XCD = bh % 8)
  const int b    = bh / NHEAD;
  const int h    = bh - b * NHEAD;
  const int tid  = threadIdx.x;
  const int wave = tid >> 6;    // 0..3
  const int lane = tid & 63;
  const int c    = lane & 15;
  const int Q0   = lane >> 4;
  const int w2   = wave & 1;    // query sub-tile
  const int kw   = wave >> 1;   // key half
  const int q0   = blockIdx.y * 128 + w2 * 64;
  const int ks   = kw * 512;

  bf16x8 Bq[4];
#pragma unroll
  for (int g = 0; g < 4; g++)
    Bq[g] = *(const bf16x8*)(qb + ((size_t)bh * NPIX + q0 + 16 * g + c) * DH + Q0 * 8);

  const unsigned short* kbase = kb + (size_t)bh * NPIX * DH;
  const unsigned short* vrow0 = vtb + ((size_t)bh * DH + c) * NPIX;
  const unsigned short* vrow1 = vtb + ((size_t)bh * DH + c + 16) * NPIX;

  const f32x4 zero = {0.f, 0.f, 0.f, 0.f};
  const bf16x8 zero8 = {0, 0, 0, 0, 0, 0, 0, 0};
  const short ONE = (short)0x3F80;  // bf16 1.0
  const bf16x8 ones = {ONE, ONE, ONE, ONE, ONE, ONE, ONE, ONE};

  f32x4 o0[4], o1[4], ls[4];
#pragma unroll
  for (int g = 0; g < 4; g++) { o0[g] = zero; o1[g] = zero; ls[g] = zero; }

  unsigned short* prow[4];
#pragma unroll
  for (int g = 0; g < 4; g++) prow[g] = &Pbuf[wave][g][c][0];

  // ---- depth-2 pipeline, NAMED slots: A holds even tiles, B odd tiles ----
  bf16x8 KA0 = *(const bf16x8*)(kbase + (size_t)(ks + c) * DH + Q0 * 8);
  bf16x8 KA1 = *(const bf16x8*)(kbase + (size_t)(ks + 16 + c) * DH + Q0 * 8);
  bf16x8 VA0 = *(const bf16x8*)(vrow0 + ks + Q0 * 8);
  bf16x8 VA1 = *(const bf16x8*)(vrow1 + ks + Q0 * 8);
  bf16x8 KB0 = *(const bf16x8*)(kbase + (size_t)(ks + 32 + c) * DH + Q0 * 8);
  bf16x8 KB1 = *(const bf16x8*)(kbase + (size_t)(ks + 48 + c) * DH + Q0 * 8);
  bf16x8 VB0 = *(const bf16x8*)(vrow0 + ks + 32 + Q0 * 8);
  bf16x8 VB1 = *(const bf16x8*)(vrow1 + ks + 32 + Q0 * 8);

  bf16x8 Vr0 = zero8, Vr1 = zero8;              // V(t-1); PV(-1) adds 0
  bf16x8 Bp[4] = {zero8, zero8, zero8, zero8};  // P(t-1)

  for (int it2 = 0; it2 < 8; it2++) {
    const int t = it2 * 2;
    attn_body(kbase, vrow0, vrow1, c, Q0, ks + (((t + 2) * 32) & 511),
              Bq, Bp, prow, o0, o1, ls, KA0, KA1, VA0, VA1, Vr0, Vr1);
    attn_body(kbase, vrow0, vrow1, c, Q0, ks + (((t + 3) * 32) & 511),
              Bq, Bp, prow, o0, o1, ls, KB0, KB1, VB0, VB1, Vr0, Vr1);
  }

  // drain the skewed pipe: PV of the last key tile (P(15) in Bp, V(15) in Vr)
#pragma unroll
  for (int g = 0; g < 4; g++) {
    o0[g] = __builtin_amdgcn_mfma_f32_16x16x32_bf16(Vr0, Bp[g], o0[g], 0, 0, 0);
    o1[g] = __builtin_amdgcn_mfma_f32_16x16x32_bf16(Vr1, Bp[g], o1[g], 0, 0, 0);
    ls[g] = __builtin_amdgcn_mfma_f32_16x16x32_bf16(ones, Bp[g], ls[g], 0, 0, 0);
  }

  // ---- key-split combine through LDS (Pbuf is dead past this point) ----
  __syncthreads();
  if (kw == 1) {
#pragma unroll
    for (int g = 0; g < 4; g++) {
      O0b[w2][g][lane] = o0[g];
      O1b[w2][g][lane] = o1[g];
      Lb[w2][g][lane]  = ls[g][0];
    }
  }
  __syncthreads();
  if (kw == 1) return;

  // store normalized O in proj's fragment-major layout:
  // row-block rb = (q0>>4)+g, k-chunk = h, row-in-block = c.
#pragma unroll
  for (int g = 0; g < 4; g++) {
    o0[g] += O0b[w2][g][lane];
    o1[g] += O1b[w2][g][lane];
    const float inv = 1.0f / (ls[g][0] + Lb[w2][g][lane]);  // full l[q]
    unsigned short* op = ao +
        (((size_t)b * 64 + (q0 >> 4) + g) * 12 + h) * 512 + c * 8 + 4 * (Q0 & 1);
    *(uint2*)(op + (Q0 >> 1) * 128) =
        (uint2){pk2(o0[g][0] * inv, o0[g][1] * inv),
                pk2(o0[g][2] * inv, o0[g][3] * inv)};
    *(uint2*)(op + (2 + (Q0 >> 1)) * 128) =
        (uint2){pk2(o1[g][0] * inv, o1[g][1] * inv),
                pk2(o1[g][2] * inv, o1[g][3] * inv)};
  }
}

// ---------------------------------------------------------------------------
// Output projection v3: LDS-free, SWIZZLED operands (pw from prep, ao from
// attn).  out[b][c][n] = sum Pw[c,c']*AO[b,n,c'] + bias[c].
// Grid x = b*8+ntile (XCD pin), y = 3 m-tiles; 384 blocks, single pass.
// ---------------------------------------------------------------------------
__global__ __launch_bounds__(256, 3) void proj_mfma(
    const unsigned short* __restrict__ aos, const unsigned short* __restrict__ pws,
    const float* __restrict__ bias, float* __restrict__ out) {
  const int bx = blockIdx.x;
  const int b  = bx >> 3;
  const int n0 = (bx & 7) * 128;
  const int m0 = blockIdx.y * 128;
  const int tid = threadIdx.x, wave = tid >> 6, lane = tid & 63;
  const int wm = (wave >> 1) * 64, wn = (wave & 1) * 64;
  const int cc = lane & 15, quad = lane >> 4;

  const unsigned short* abase =
      pws + ((size_t)((m0 + wm) >> 4) * 12) * 512 + lane * 8;
  const unsigned short* bbase =
      aos + (((size_t)b * 64 + ((n0 + wn) >> 4)) * 12) * 512 + lane * 8;

  f32x4 acc[4][4];
#pragma unroll
  for (int i = 0; i < 4; i++)
#pragma unroll
    for (int j = 0; j < 4; j++) acc[i][j] = (f32x4){0.f, 0.f, 0.f, 0.f};

  bf16x8 af[4], bfr[4];
#pragma unroll
  for (int t = 0; t < 4; t++) af[t] = *(const bf16x8*)(abase + (size_t)(t * 12) * 512);
#pragma unroll
  for (int t = 0; t < 4; t++) bfr[t] = *(const bf16x8*)(bbase + (size_t)(t * 12) * 512);

#pragma unroll 2
  for (int kc = 0; kc < 12; kc++) {
    const int k2 = (kc + 1 < 12) ? kc + 1 : 0;
    bf16x8 naf[4], nbf[4];
#pragma unroll
    for (int t = 0; t < 4; t++)
      naf[t] = *(const bf16x8*)(abase + (size_t)(t * 12 + k2) * 512);
#pragma unroll
    for (int t = 0; t < 4; t++)
      nbf[t] = *(const bf16x8*)(bbase + (size_t)(t * 12 + k2) * 512);
#pragma unroll
    for (int i = 0; i < 4; i++)
#pragma unroll
      for (int j = 0; j < 4; j++)
        acc[i][j] = __builtin_amdgcn_mfma_f32_16x16x32_bf16(af[i], bfr[j], acc[i][j], 0, 0, 0);
#pragma unroll
    for (int t = 0; t < 4; t++) { af[t] = naf[t]; bfr[t] = nbf[t]; }
  }

#pragma unroll
  for (int mt = 0; mt < 4; mt++) {
    const int cbase = m0 + wm + mt * 16 + quad * 4;
    const float4 bi4 = *(const float4*)(bias + cbase);
#pragma unroll
    for (int nt = 0; nt < 4; nt++) {
      const int n = n0 + wn + nt * 16 + cc;
      float* op = out + ((size_t)b * CH + cbase) * NPIX + n;
      op[0 * NPIX] = acc[mt][nt][0] + bi4.x;
      op[1 * NPIX] = acc[mt][nt][1] + bi4.y;
      op[2 * NPIX] = acc[mt][nt][2] + bi4.z;
      op[3 * NPIX] = acc[mt][nt][3] + bi4.w;
    }
  }
}

extern "C" void kernel_launch(void* const* d_in, const int* in_sizes, int n_in,
                              void* d_out, int out_size, void* d_ws, size_t ws_size,
                              hipStream_t stream) {
  const float* x      = (const float*)d_in[0];  // [16,384,32,32]
  const float* qkv_w  = (const float*)d_in[1];  // [1152,384]
  const float* proj_w = (const float*)d_in[2];  // [384,384]
  const float* proj_b = (const float*)d_in[3];  // [384]

  constexpr size_t SEG = (size_t)NB * NPIX * CH;  // 6291456
  unsigned short* ws  = (unsigned short*)d_ws;
  unsigned short* xtw = ws;                         // swizzled
  unsigned short* qbw = ws + SEG;
  unsigned short* kbw = ws + 2 * SEG;
  unsigned short* vtw = ws + 3 * SEG;
  unsigned short* aow = ws + 4 * SEG;               // swizzled
  unsigned short* wqw = ws + 5 * SEG;               // swizzled, 442368
  unsigned short* pww = wqw + (size_t)3 * CH * CH;  // swizzled, 147456

  prep_fused<<<2112, 256, 0, stream>>>(x, qkv_w, proj_w, xtw, wqw, pww);
  // grid x = b*8+ntile: XCD = x%8 pins each xt slice; y = 9 m-tiles
  qkv_mfma<<<dim3(NB * (NPIX / 128), (3 * CH) / 128), 256, 0, stream>>>(xtw, wqw, qbw, kbw, vtw);
  // grid (bh, qtile): same-bh blocks share an XCD -> K/V L2-resident;
  // 4-wave blocks, 128 queries/block, key-split x2, depth-2 K/V pipeline
  attn_mfma<<<dim3(NB * NHEAD, NPIX / 128), 256, 0, stream>>>(qbw, kbw, vtw, aow);
  proj_mfma<<<dim3(NB * (NPIX / 128), CH / 128), 256, 0, stream>>>(aow, pww, proj_b, (float*)d_out);
}

// Round 10
// 188.777 us; speedup vs baseline: 1.0503x; 1.0503x over previous
//
#include <hip/hip_runtime.h>

// Problem constants (fixed by the reference)
constexpr int CH    = 384;    // channels
constexpr int NPIX  = 1024;   // H*W = 32*32
constexpr int NHEAD = 12;
constexpr int DH    = 32;     // head dim
constexpr int NB    = 16;     // batch
constexpr float SCALE = 0.17677669529663689f;  // 32^-0.5
constexpr float LOG2E = 1.4426950408889634f;

typedef __attribute__((ext_vector_type(8))) short bf16x8;  // 8 bf16 (4 VGPRs)
typedef __attribute__((ext_vector_type(4))) float f32x4;   // MFMA C/D frag

// Fragment-major ("swizzled") operand layout for the LDS-free GEMMs:
// a K-major matrix [R][384] is stored as [R/16][12] blocks of 512 bf16;
// within a block, lane (quad*16+cc) holds row cc, k = quad*8..+7 of the
// 32-wide k-chunk, at offset lane*8.  A fragment load is then
// base + lane*8 -> 1 KB fully coalesced per wave instruction.
// elem (r, ch):  off = ((r>>4)*12 + (ch>>5))*512 + (((ch>>3)&3)*16 + (r&15))*8 + (ch&7)

// pack two fp32 -> two bf16, round-half-up (3 VALU)
__device__ __forceinline__ unsigned pk2(float a, float b) {
  return __builtin_amdgcn_perm(__float_as_uint(b) + 0x8000u,
                               __float_as_uint(a) + 0x8000u, 0x07060302u);
}
// pack two fp32 -> two bf16, TRUNCATE (1 VALU) — P only; bias cancels in P/l.
__device__ __forceinline__ unsigned pk2t(float a, float b) {
  return __builtin_amdgcn_perm(__float_as_uint(b), __float_as_uint(a), 0x07060302u);
}

// 2^x on the VALU (v_exp_f32 computes 2^x natively)
#if __has_builtin(__builtin_amdgcn_exp2f)
#define EXP2F(x) __builtin_amdgcn_exp2f(x)
#else
#define EXP2F(x) exp2f(x)
#endif

// ---------------------------------------------------------------------------
// Fused prep: blocks [0,1536) transpose x [b][c][n] fp32 -> xt swizzled bf16
// (per batch: 64 row-blocks x 12 k-chunks); blocks [1536,2112) convert
// weights to swizzled bf16 (Q rows pre-scaled by SCALE*log2e: base-2 logits).
// ---------------------------------------------------------------------------
__global__ __launch_bounds__(256) void prep_fused(
    const float* __restrict__ x, const float* __restrict__ qw,
    const float* __restrict__ pw, unsigned short* __restrict__ xts,
    unsigned short* __restrict__ wqs, unsigned short* __restrict__ pws) {
  const int bx = blockIdx.x;
  const int tid = threadIdx.x;
  if (bx < 1536) {
    __shared__ float T[64][65];
    const int b = bx / 96, rem = bx - b * 96;
    const int c0 = (rem >> 4) * 64, n0 = (rem & 15) * 64;
    const float* xb = x + ((size_t)b * CH + c0) * NPIX + n0;
    const int rn = (tid & 15) * 4, rc = tid >> 4;
#pragma unroll
    for (int i = 0; i < 4; i++) {
      float4 v = *(const float4*)(xb + (size_t)(rc + i * 16) * NPIX + rn);
      T[rc + i * 16][rn + 0] = v.x;
      T[rc + i * 16][rn + 1] = v.y;
      T[rc + i * 16][rn + 2] = v.z;
      T[rc + i * 16][rn + 3] = v.w;
    }
    __syncthreads();
    const int wc = (tid & 15) * 4;  // channel offset within the 64-wide c tile
    const int ch = c0 + wc;         // 4 consecutive channels, j = ch&7 in {0,4}
    const int kc = ch >> 5, qd = (ch >> 3) & 3, j = ch & 7;
#pragma unroll
    for (int i = 0; i < 4; i++) {
      const int nl = (tid >> 4) + i * 16;       // local pixel row
      const int ng = n0 + nl;
      uint2 p = {pk2(T[wc][nl], T[wc + 1][nl]), pk2(T[wc + 2][nl], T[wc + 3][nl])};
      size_t off = (((size_t)b * 64 + (ng >> 4)) * 12 + kc) * 512 +
                   (qd * 16 + (ng & 15)) * 8 + j;
      *(uint2*)(xts + off) = p;
    }
  } else {
    const int idx = (bx - 1536) * 256 + tid;
    if (idx < 110592) {
      float4 v = ((const float4*)qw)[idx];
      const int o  = (idx * 4) / CH;  // 4 | 384: never crosses a row
      const int ch = (idx * 4) - o * CH;
      const float sc = (o < CH) ? SCALE * LOG2E : 1.0f;
      size_t off = (((size_t)(o >> 4)) * 12 + (ch >> 5)) * 512 +
                   (((ch >> 3) & 3) * 16 + (o & 15)) * 8 + (ch & 7);
      *(uint2*)(wqs + off) =
          (uint2){pk2(v.x * sc, v.y * sc), pk2(v.z * sc, v.w * sc)};
    } else {
      const int jdx = idx - 110592;
      float4 v = ((const float4*)pw)[jdx];
      const int o  = (jdx * 4) / CH;
      const int ch = (jdx * 4) - o * CH;
      size_t off = (((size_t)(o >> 4)) * 12 + (ch >> 5)) * 512 +
                   (((ch >> 3) & 3) * 16 + (o & 15)) * 8 + (ch & 7);
      *(uint2*)(pws + off) = (uint2){pk2(v.x, v.y), pk2(v.z, v.w)};
    }
  }
}

// ---------------------------------------------------------------------------
// QKV GEMM v3: LDS-free, SWIZZLED operands.  Y[o, b*1024+n] = Wq.XT^T.
// Every fragment load is base + lane*8 (1 KB coalesced); 1-iter register
// prefetch; no barriers, no LDS, no waitcnt drains.  Grid x = b*8+ntile
// pins each batch's xt slice to one XCD.  V-blocks swap MFMA operands so
// C rows = consecutive pixels -> vectorized d-major stores.
// ---------------------------------------------------------------------------
__global__ __launch_bounds__(256, 3) void qkv_mfma(
    const unsigned short* __restrict__ xts, const unsigned short* __restrict__ wqs,
    unsigned short* __restrict__ qb, unsigned short* __restrict__ kb,
    unsigned short* __restrict__ vtb) {
  const int bx = blockIdx.x;          // b = bx>>3, ntile = bx&7
  const int b  = bx >> 3;
  const int n0 = (bx & 7) * 128;
  const int m0 = blockIdx.y * 128;    // 0..8
  const int qkv_t = blockIdx.y / 3;   // 0=Q, 1=K, 2=V
  const int tid = threadIdx.x, wave = tid >> 6, lane = tid & 63;
  const int wm = (wave >> 1) * 64, wn = (wave & 1) * 64;
  const int cc = lane & 15, quad = lane >> 4;

  const unsigned short* abase =
      wqs + ((size_t)((m0 + wm) >> 4) * 12) * 512 + lane * 8;
  const unsigned short* bbase =
      xts + (((size_t)b * 64 + ((n0 + wn) >> 4)) * 12) * 512 + lane * 8;

  f32x4 acc[4][4];
#pragma unroll
  for (int i = 0; i < 4; i++)
#pragma unroll
    for (int j = 0; j < 4; j++) acc[i][j] = (f32x4){0.f, 0.f, 0.f, 0.f};

  bf16x8 af[4], bfr[4];
#pragma unroll
  for (int t = 0; t < 4; t++) af[t] = *(const bf16x8*)(abase + (size_t)(t * 12) * 512);
#pragma unroll
  for (int t = 0; t < 4; t++) bfr[t] = *(const bf16x8*)(bbase + (size_t)(t * 12) * 512);

#pragma unroll 2
  for (int kc = 0; kc < 12; kc++) {
    const int k2 = (kc + 1 < 12) ? kc + 1 : 0;  // wrap: redundant, in-bounds
    bf16x8 naf[4], nbf[4];
#pragma unroll
    for (int t = 0; t < 4; t++)
      naf[t] = *(const bf16x8*)(abase + (size_t)(t * 12 + k2) * 512);
#pragma unroll
    for (int t = 0; t < 4; t++)
      nbf[t] = *(const bf16x8*)(bbase + (size_t)(t * 12 + k2) * 512);

    if (qkv_t < 2) {
#pragma unroll
      for (int i = 0; i < 4; i++)
#pragma unroll
        for (int j = 0; j < 4; j++)
          acc[i][j] = __builtin_amdgcn_mfma_f32_16x16x32_bf16(af[i], bfr[j], acc[i][j], 0, 0, 0);
    } else {  // V: swap -> C rows = pixels, cols = weight-o
#pragma unroll
      for (int i = 0; i < 4; i++)
#pragma unroll
        for (int j = 0; j < 4; j++)
          acc[i][j] = __builtin_amdgcn_mfma_f32_16x16x32_bf16(bfr[i], af[j], acc[i][j], 0, 0, 0);
    }
#pragma unroll
    for (int t = 0; t < 4; t++) { af[t] = naf[t]; bfr[t] = nbf[t]; }
  }

  const int obase = m0 - qkv_t * CH;  // 0/128/256 within the Q/K/V segment
  if (qkv_t < 2) {
    unsigned short* dst0 = (qkv_t == 0) ? qb : kb;
#pragma unroll
    for (int mt = 0; mt < 4; mt++) {
      const int o = obase + wm + mt * 16 + quad * 4;  // [0,384)
      const int h = o >> 5, d0 = o & 31;
      unsigned short* drow = dst0 + ((size_t)(b * NHEAD + h) * NPIX) * DH + d0;
#pragma unroll
      for (int nt = 0; nt < 4; nt++) {
        const int n = n0 + wn + nt * 16 + cc;
        uint2 p = {pk2(acc[mt][nt][0], acc[mt][nt][1]),
                   pk2(acc[mt][nt][2], acc[mt][nt][3])};
        *(uint2*)(drow + (size_t)n * DH) = p;
      }
    }
  } else {
#pragma unroll
    for (int i = 0; i < 4; i++) {
      const int nbase = n0 + wn + i * 16 + quad * 4;
#pragma unroll
      for (int j = 0; j < 4; j++) {
        const int od = obase + wm + j * 16 + cc;
        const int h = od >> 5, dd = od & 31;
        unsigned short* vrow = vtb + ((size_t)(b * NHEAD + h) * DH + dd) * NPIX;
        *(uint2*)(vrow + nbase) = (uint2){pk2(acc[i][j][0], acc[i][j][1]),
                                          pk2(acc[i][j][2], acc[i][j][3])};
      }
    }
  }
}

// ---------------------------------------------------------------------------
// MFMA attention — EXACT R3 body (62.7 us proven): 64 q/wave, x32 MFMAs,
// LDS P roundtrip (PSTR=36), key-split x2 in a 4-wave block, combine via
// LDS overlay.  Stamped twice via macro: lb3 (launch_bounds(256,3), the
// proven config) handles queries [0,512); lb4 (launch_bounds(256,4)) handles
// [512,1024) — a within-run A/B testing whether capping UNIFIED (VGPR+AGPR)
// registers at 128/wave lifts the 2-waves/SIMD occupancy ceiling that every
// round has measured (~25% occupancy regardless of grid).  Arch VGPR is 80;
// accumulators ~48 AGPR: 128 is exactly borderline by design.
// Tripwire: lb4 WRITE_SIZE >> 6 MB = spill -> ship pure R3 next round.
// ---------------------------------------------------------------------------
#define ATTN_BODY(QOFF)                                                        \
  constexpr int PSTR = 36;                                                     \
  __shared__ __align__(16) unsigned char smem[18432];                          \
  unsigned short (*Pbuf)[4][16][PSTR] =                                        \
      reinterpret_cast<unsigned short(*)[4][16][PSTR]>(smem);                  \
  f32x4 (*O0b)[4][64] = reinterpret_cast<f32x4(*)[4][64]>(smem);               \
  f32x4 (*O1b)[4][64] = reinterpret_cast<f32x4(*)[4][64]>(smem + 8192);        \
  float (*Lb)[4][64]  = reinterpret_cast<float(*)[4][64]>(smem + 16384);       \
  const int bh   = blockIdx.x;                                                 \
  const int b    = bh / NHEAD;                                                 \
  const int h    = bh - b * NHEAD;                                             \
  const int tid  = threadIdx.x;                                                \
  const int wave = tid >> 6;                                                   \
  const int lane = tid & 63;                                                   \
  const int c    = lane & 15;                                                  \
  const int Q0   = lane >> 4;                                                  \
  const int w2   = wave & 1;                                                   \
  const int kw   = wave >> 1;                                                  \
  const int q0   = (blockIdx.y + (QOFF)) * 128 + w2 * 64;                      \
  const int ks   = kw * 512;                                                   \
  bf16x8 Bq[4];                                                                \
  _Pragma("unroll")                                                            \
  for (int g = 0; g < 4; g++)                                                  \
    Bq[g] = *(const bf16x8*)(qb + ((size_t)bh * NPIX + q0 + 16 * g + c) * DH + \
                             Q0 * 8);                                          \
  const unsigned short* kbase = kb + (size_t)bh * NPIX * DH;                   \
  const unsigned short* vrow0 = vtb + ((size_t)bh * DH + c) * NPIX;            \
  const unsigned short* vrow1 = vtb + ((size_t)bh * DH + c + 16) * NPIX;       \
  const f32x4 zero = {0.f, 0.f, 0.f, 0.f};                                     \
  const bf16x8 zero8 = {0, 0, 0, 0, 0, 0, 0, 0};                               \
  const short ONE = (short)0x3F80;                                             \
  const bf16x8 ones = {ONE, ONE, ONE, ONE, ONE, ONE, ONE, ONE};                \
  f32x4 o0[4], o1[4], ls[4];                                                   \
  _Pragma("unroll")                                                            \
  for (int g = 0; g < 4; g++) { o0[g] = zero; o1[g] = zero; ls[g] = zero; }    \
  unsigned short* prow[4];                                                     \
  _Pragma("unroll")                                                            \
  for (int g = 0; g < 4; g++) prow[g] = &Pbuf[wave][g][c][0];                  \
  bf16x8 Ka0 = *(const bf16x8*)(kbase + (size_t)(ks + c) * DH + Q0 * 8);       \
  bf16x8 Ka1 = *(const bf16x8*)(kbase + (size_t)(ks + 16 + c) * DH + Q0 * 8);  \
  bf16x8 Vr0 = zero8, Vr1 = zero8;                                             \
  bf16x8 Bp[4] = {zero8, zero8, zero8, zero8};                                 \
  _Pragma("unroll 2")                                                          \
  for (int kt = ks; kt < ks + 512; kt += 32) {                                 \
    const int kt2 = ks + (((kt - ks) + 32) & 511);                             \
    bf16x8 nKa0 = *(const bf16x8*)(kbase + (size_t)(kt2 + c) * DH + Q0 * 8);   \
    bf16x8 nKa1 =                                                              \
        *(const bf16x8*)(kbase + (size_t)(kt2 + 16 + c) * DH + Q0 * 8);        \
    bf16x8 nVa0 = *(const bf16x8*)(vrow0 + kt + Q0 * 8);                       \
    bf16x8 nVa1 = *(const bf16x8*)(vrow1 + kt + Q0 * 8);                       \
    f32x4 s0[4], s1[4];                                                        \
    _Pragma("unroll")                                                          \
    for (int g = 0; g < 4; g++) {                                              \
      s0[g] = __builtin_amdgcn_mfma_f32_16x16x32_bf16(Ka0, Bq[g], zero, 0, 0, 0); \
      s1[g] = __builtin_amdgcn_mfma_f32_16x16x32_bf16(Ka1, Bq[g], zero, 0, 0, 0); \
    }                                                                          \
    _Pragma("unroll")                                                          \
    for (int g = 0; g < 4; g++) {                                              \
      o0[g] = __builtin_amdgcn_mfma_f32_16x16x32_bf16(Vr0, Bp[g], o0[g], 0, 0, 0); \
      o1[g] = __builtin_amdgcn_mfma_f32_16x16x32_bf16(Vr1, Bp[g], o1[g], 0, 0, 0); \
      ls[g] = __builtin_amdgcn_mfma_f32_16x16x32_bf16(ones, Bp[g], ls[g], 0, 0, 0); \
    }                                                                          \
    _Pragma("unroll")                                                          \
    for (int g = 0; g < 4; g++) {                                              \
      float p0[4], p1[4];                                                      \
      _Pragma("unroll")                                                        \
      for (int r = 0; r < 4; r++) p0[r] = EXP2F(s0[g][r]);                     \
      _Pragma("unroll")                                                        \
      for (int r = 0; r < 4; r++) p1[r] = EXP2F(s1[g][r]);                     \
      *(uint2*)(prow[g] + 4 * Q0) =                                            \
          (uint2){pk2t(p0[0], p0[1]), pk2t(p0[2], p0[3])};                     \
      *(uint2*)(prow[g] + 16 + 4 * Q0) =                                       \
          (uint2){pk2t(p1[0], p1[1]), pk2t(p1[2], p1[3])};                     \
    }                                                                          \
    _Pragma("unroll")                                                          \
    for (int g = 0; g < 4; g++) Bp[g] = *(const bf16x8*)(prow[g] + 8 * Q0);    \
    Ka0 = nKa0; Ka1 = nKa1; Vr0 = nVa0; Vr1 = nVa1;                            \
  }                                                                            \
  _Pragma("unroll")                                                            \
  for (int g = 0; g < 4; g++) {                                                \
    o0[g] = __builtin_amdgcn_mfma_f32_16x16x32_bf16(Vr0, Bp[g], o0[g], 0, 0, 0); \
    o1[g] = __builtin_amdgcn_mfma_f32_16x16x32_bf16(Vr1, Bp[g], o1[g], 0, 0, 0); \
    ls[g] = __builtin_amdgcn_mfma_f32_16x16x32_bf16(ones, Bp[g], ls[g], 0, 0, 0); \
  }                                                                            \
  __syncthreads();                                                             \
  if (kw == 1) {                                                               \
    _Pragma("unroll")                                                          \
    for (int g = 0; g < 4; g++) {                                              \
      O0b[w2][g][lane] = o0[g];                                                \
      O1b[w2][g][lane] = o1[g];                                                \
      Lb[w2][g][lane]  = ls[g][0];                                             \
    }                                                                          \
  }                                                                            \
  __syncthreads();                                                             \
  if (kw == 1) return;                                                         \
  _Pragma("unroll")                                                            \
  for (int g = 0; g < 4; g++) {                                                \
    o0[g] += O0b[w2][g][lane];                                                 \
    o1[g] += O1b[w2][g][lane];                                                 \
    const float inv = 1.0f / (ls[g][0] + Lb[w2][g][lane]);                     \
    unsigned short* op = ao +                                                  \
        (((size_t)b * 64 + (q0 >> 4) + g) * 12 + h) * 512 + c * 8 +            \
        4 * (Q0 & 1);                                                          \
    *(uint2*)(op + (Q0 >> 1) * 128) =                                          \
        (uint2){pk2(o0[g][0] * inv, o0[g][1] * inv),                           \
                pk2(o0[g][2] * inv, o0[g][3] * inv)};                          \
    *(uint2*)(op + (2 + (Q0 >> 1)) * 128) =                                    \
        (uint2){pk2(o1[g][0] * inv, o1[g][1] * inv),                           \
                pk2(o1[g][2] * inv, o1[g][3] * inv)};                          \
  }

__global__ __launch_bounds__(256, 3) void attn_mfma_lb3(
    const unsigned short* __restrict__ qb, const unsigned short* __restrict__ kb,
    const unsigned short* __restrict__ vtb, unsigned short* __restrict__ ao) {
  ATTN_BODY(0)
}

__global__ __launch_bounds__(256, 4) void attn_mfma_lb4(
    const unsigned short* __restrict__ qb, const unsigned short* __restrict__ kb,
    const unsigned short* __restrict__ vtb, unsigned short* __restrict__ ao) {
  ATTN_BODY(4)
}

// ---------------------------------------------------------------------------
// Output projection v3: LDS-free, SWIZZLED operands (pw from prep, ao from
// attn).  out[b][c][n] = sum Pw[c,c']*AO[b,n,c'] + bias[c].
// Grid x = b*8+ntile (XCD pin), y = 3 m-tiles; 384 blocks, single pass.
// ---------------------------------------------------------------------------
__global__ __launch_bounds__(256, 3) void proj_mfma(
    const unsigned short* __restrict__ aos, const unsigned short* __restrict__ pws,
    const float* __restrict__ bias, float* __restrict__ out) {
  const int bx = blockIdx.x;
  const int b  = bx >> 3;
  const int n0 = (bx & 7) * 128;
  const int m0 = blockIdx.y * 128;
  const int tid = threadIdx.x, wave = tid >> 6, lane = tid & 63;
  const int wm = (wave >> 1) * 64, wn = (wave & 1) * 64;
  const int cc = lane & 15, quad = lane >> 4;

  const unsigned short* abase =
      pws + ((size_t)((m0 + wm) >> 4) * 12) * 512 + lane * 8;
  const unsigned short* bbase =
      aos + (((size_t)b * 64 + ((n0 + wn) >> 4)) * 12) * 512 + lane * 8;

  f32x4 acc[4][4];
#pragma unroll
  for (int i = 0; i < 4; i++)
#pragma unroll
    for (int j = 0; j < 4; j++) acc[i][j] = (f32x4){0.f, 0.f, 0.f, 0.f};

  bf16x8 af[4], bfr[4];
#pragma unroll
  for (int t = 0; t < 4; t++) af[t] = *(const bf16x8*)(abase + (size_t)(t * 12) * 512);
#pragma unroll
  for (int t = 0; t < 4; t++) bfr[t] = *(const bf16x8*)(bbase + (size_t)(t * 12) * 512);

#pragma unroll 2
  for (int kc = 0; kc < 12; kc++) {
    const int k2 = (kc + 1 < 12) ? kc + 1 : 0;
    bf16x8 naf[4], nbf[4];
#pragma unroll
    for (int t = 0; t < 4; t++)
      naf[t] = *(const bf16x8*)(abase + (size_t)(t * 12 + k2) * 512);
#pragma unroll
    for (int t = 0; t < 4; t++)
      nbf[t] = *(const bf16x8*)(bbase + (size_t)(t * 12 + k2) * 512);
#pragma unroll
    for (int i = 0; i < 4; i++)
#pragma unroll
      for (int j = 0; j < 4; j++)
        acc[i][j] = __builtin_amdgcn_mfma_f32_16x16x32_bf16(af[i], bfr[j], acc[i][j], 0, 0, 0);
#pragma unroll
    for (int t = 0; t < 4; t++) { af[t] = naf[t]; bfr[t] = nbf[t]; }
  }

#pragma unroll
  for (int mt = 0; mt < 4; mt++) {
    const int cbase = m0 + wm + mt * 16 + quad * 4;
    const float4 bi4 = *(const float4*)(bias + cbase);
#pragma unroll
    for (int nt = 0; nt < 4; nt++) {
      const int n = n0 + wn + nt * 16 + cc;
      float* op = out + ((size_t)b * CH + cbase) * NPIX + n;
      op[0 * NPIX] = acc[mt][nt][0] + bi4.x;
      op[1 * NPIX] = acc[mt][nt][1] + bi4.y;
      op[2 * NPIX] = acc[mt][nt][2] + bi4.z;
      op[3 * NPIX] = acc[mt][nt][3] + bi4.w;
    }
  }
}

extern "C" void kernel_launch(void* const* d_in, const int* in_sizes, int n_in,
                              void* d_out, int out_size, void* d_ws, size_t ws_size,
                              hipStream_t stream) {
  const float* x      = (const float*)d_in[0];  // [16,384,32,32]
  const float* qkv_w  = (const float*)d_in[1];  // [1152,384]
  const float* proj_w = (const float*)d_in[2];  // [384,384]
  const float* proj_b = (const float*)d_in[3];  // [384]

  constexpr size_t SEG = (size_t)NB * NPIX * CH;  // 6291456
  unsigned short* ws  = (unsigned short*)d_ws;
  unsigned short* xtw = ws;                         // swizzled
  unsigned short* qbw = ws + SEG;
  unsigned short* kbw = ws + 2 * SEG;
  unsigned short* vtw = ws + 3 * SEG;
  unsigned short* aow = ws + 4 * SEG;               // swizzled
  unsigned short* wqw = ws + 5 * SEG;               // swizzled, 442368
  unsigned short* pww = wqw + (size_t)3 * CH * CH;  // swizzled, 147456

  prep_fused<<<2112, 256, 0, stream>>>(x, qkv_w, proj_w, xtw, wqw, pww);
  // grid x = b*8+ntile: XCD = x%8 pins each xt slice; y = 9 m-tiles
  qkv_mfma<<<dim3(NB * (NPIX / 128), (3 * CH) / 128), 256, 0, stream>>>(xtw, wqw, qbw, kbw, vtw);
  // attn split for within-run A/B: lb3 = proven R3 config (queries 0..511),
  // lb4 = unified-register-capped variant (queries 512..1023).
  attn_mfma_lb3<<<dim3(NB * NHEAD, 4), 256, 0, stream>>>(qbw, kbw, vtw, aow);
  attn_mfma_lb4<<<dim3(NB * NHEAD, 4), 256, 0, stream>>>(qbw, kbw, vtw, aow);
  proj_mfma<<<dim3(NB * (NPIX / 128), CH / 128), 256, 0, stream>>>(aow, pww, proj_b, (float*)d_out);
}

// Round 11
// 185.056 us; speedup vs baseline: 1.0715x; 1.0201x over previous
//
#include <hip/hip_runtime.h>

// Problem constants (fixed by the reference)
constexpr int CH    = 384;    // channels
constexpr int NPIX  = 1024;   // H*W = 32*32
constexpr int NHEAD = 12;
constexpr int DH    = 32;     // head dim
constexpr int NB    = 16;     // batch
constexpr float SCALE = 0.17677669529663689f;  // 32^-0.5
constexpr float LOG2E = 1.4426950408889634f;

typedef __attribute__((ext_vector_type(8))) short bf16x8;  // 8 bf16 (4 VGPRs)
typedef __attribute__((ext_vector_type(4))) float f32x4;   // MFMA C/D frag

// Fragment-major ("swizzled") operand layout for the LDS-free GEMMs:
// a K-major matrix [R][384] is stored as [R/16][12] blocks of 512 bf16;
// within a block, lane (quad*16+cc) holds row cc, k = quad*8..+7 of the
// 32-wide k-chunk, at offset lane*8.  A fragment load is then
// base + lane*8 -> 1 KB fully coalesced per wave instruction.
// elem (r, ch):  off = ((r>>4)*12 + (ch>>5))*512 + (((ch>>3)&3)*16 + (r&15))*8 + (ch&7)

// pack two fp32 -> two bf16, round-half-up (3 VALU)
__device__ __forceinline__ unsigned pk2(float a, float b) {
  return __builtin_amdgcn_perm(__float_as_uint(b) + 0x8000u,
                               __float_as_uint(a) + 0x8000u, 0x07060302u);
}
// pack two fp32 -> two bf16, TRUNCATE (1 VALU) — P only; bias cancels in P/l.
__device__ __forceinline__ unsigned pk2t(float a, float b) {
  return __builtin_amdgcn_perm(__float_as_uint(b), __float_as_uint(a), 0x07060302u);
}

// 2^x on the VALU (v_exp_f32 computes 2^x natively)
#if __has_builtin(__builtin_amdgcn_exp2f)
#define EXP2F(x) __builtin_amdgcn_exp2f(x)
#else
#define EXP2F(x) exp2f(x)
#endif

// ---------------------------------------------------------------------------
// Fused prep: blocks [0,1536) transpose x [b][c][n] fp32 -> xt swizzled bf16
// (per batch: 64 row-blocks x 12 k-chunks); blocks [1536,2112) convert
// weights to swizzled bf16 (Q rows pre-scaled by SCALE*log2e: base-2 logits).
// ---------------------------------------------------------------------------
__global__ __launch_bounds__(256) void prep_fused(
    const float* __restrict__ x, const float* __restrict__ qw,
    const float* __restrict__ pw, unsigned short* __restrict__ xts,
    unsigned short* __restrict__ wqs, unsigned short* __restrict__ pws) {
  const int bx = blockIdx.x;
  const int tid = threadIdx.x;
  if (bx < 1536) {
    __shared__ float T[64][65];
    const int b = bx / 96, rem = bx - b * 96;
    const int c0 = (rem >> 4) * 64, n0 = (rem & 15) * 64;
    const float* xb = x + ((size_t)b * CH + c0) * NPIX + n0;
    const int rn = (tid & 15) * 4, rc = tid >> 4;
#pragma unroll
    for (int i = 0; i < 4; i++) {
      float4 v = *(const float4*)(xb + (size_t)(rc + i * 16) * NPIX + rn);
      T[rc + i * 16][rn + 0] = v.x;
      T[rc + i * 16][rn + 1] = v.y;
      T[rc + i * 16][rn + 2] = v.z;
      T[rc + i * 16][rn + 3] = v.w;
    }
    __syncthreads();
    const int wc = (tid & 15) * 4;  // channel offset within the 64-wide c tile
    const int ch = c0 + wc;         // 4 consecutive channels, j = ch&7 in {0,4}
    const int kc = ch >> 5, qd = (ch >> 3) & 3, j = ch & 7;
#pragma unroll
    for (int i = 0; i < 4; i++) {
      const int nl = (tid >> 4) + i * 16;       // local pixel row
      const int ng = n0 + nl;
      uint2 p = {pk2(T[wc][nl], T[wc + 1][nl]), pk2(T[wc + 2][nl], T[wc + 3][nl])};
      size_t off = (((size_t)b * 64 + (ng >> 4)) * 12 + kc) * 512 +
                   (qd * 16 + (ng & 15)) * 8 + j;
      *(uint2*)(xts + off) = p;
    }
  } else {
    const int idx = (bx - 1536) * 256 + tid;
    if (idx < 110592) {
      float4 v = ((const float4*)qw)[idx];
      const int o  = (idx * 4) / CH;  // 4 | 384: never crosses a row
      const int ch = (idx * 4) - o * CH;
      const float sc = (o < CH) ? SCALE * LOG2E : 1.0f;
      size_t off = (((size_t)(o >> 4)) * 12 + (ch >> 5)) * 512 +
                   (((ch >> 3) & 3) * 16 + (o & 15)) * 8 + (ch & 7);
      *(uint2*)(wqs + off) =
          (uint2){pk2(v.x * sc, v.y * sc), pk2(v.z * sc, v.w * sc)};
    } else {
      const int jdx = idx - 110592;
      float4 v = ((const float4*)pw)[jdx];
      const int o  = (jdx * 4) / CH;
      const int ch = (jdx * 4) - o * CH;
      size_t off = (((size_t)(o >> 4)) * 12 + (ch >> 5)) * 512 +
                   (((ch >> 3) & 3) * 16 + (o & 15)) * 8 + (ch & 7);
      *(uint2*)(pws + off) = (uint2){pk2(v.x, v.y), pk2(v.z, v.w)};
    }
  }
}

// ---------------------------------------------------------------------------
// QKV GEMM v3: LDS-free, SWIZZLED operands.  Y[o, b*1024+n] = Wq.XT^T.
// Every fragment load is base + lane*8 (1 KB coalesced); 1-iter register
// prefetch; no barriers, no LDS, no waitcnt drains.  Grid x = b*8+ntile
// pins each batch's xt slice to one XCD.  V-blocks swap MFMA operands so
// C rows = consecutive pixels -> vectorized d-major stores.
// ---------------------------------------------------------------------------
__global__ __launch_bounds__(256, 3) void qkv_mfma(
    const unsigned short* __restrict__ xts, const unsigned short* __restrict__ wqs,
    unsigned short* __restrict__ qb, unsigned short* __restrict__ kb,
    unsigned short* __restrict__ vtb) {
  const int bx = blockIdx.x;          // b = bx>>3, ntile = bx&7
  const int b  = bx >> 3;
  const int n0 = (bx & 7) * 128;
  const int m0 = blockIdx.y * 128;    // 0..8
  const int qkv_t = blockIdx.y / 3;   // 0=Q, 1=K, 2=V
  const int tid = threadIdx.x, wave = tid >> 6, lane = tid & 63;
  const int wm = (wave >> 1) * 64, wn = (wave & 1) * 64;
  const int cc = lane & 15, quad = lane >> 4;

  const unsigned short* abase =
      wqs + ((size_t)((m0 + wm) >> 4) * 12) * 512 + lane * 8;
  const unsigned short* bbase =
      xts + (((size_t)b * 64 + ((n0 + wn) >> 4)) * 12) * 512 + lane * 8;

  f32x4 acc[4][4];
#pragma unroll
  for (int i = 0; i < 4; i++)
#pragma unroll
    for (int j = 0; j < 4; j++) acc[i][j] = (f32x4){0.f, 0.f, 0.f, 0.f};

  bf16x8 af[4], bfr[4];
#pragma unroll
  for (int t = 0; t < 4; t++) af[t] = *(const bf16x8*)(abase + (size_t)(t * 12) * 512);
#pragma unroll
  for (int t = 0; t < 4; t++) bfr[t] = *(const bf16x8*)(bbase + (size_t)(t * 12) * 512);

#pragma unroll 2
  for (int kc = 0; kc < 12; kc++) {
    const int k2 = (kc + 1 < 12) ? kc + 1 : 0;  // wrap: redundant, in-bounds
    bf16x8 naf[4], nbf[4];
#pragma unroll
    for (int t = 0; t < 4; t++)
      naf[t] = *(const bf16x8*)(abase + (size_t)(t * 12 + k2) * 512);
#pragma unroll
    for (int t = 0; t < 4; t++)
      nbf[t] = *(const bf16x8*)(bbase + (size_t)(t * 12 + k2) * 512);

    if (qkv_t < 2) {
#pragma unroll
      for (int i = 0; i < 4; i++)
#pragma unroll
        for (int j = 0; j < 4; j++)
          acc[i][j] = __builtin_amdgcn_mfma_f32_16x16x32_bf16(af[i], bfr[j], acc[i][j], 0, 0, 0);
    } else {  // V: swap -> C rows = pixels, cols = weight-o
#pragma unroll
      for (int i = 0; i < 4; i++)
#pragma unroll
        for (int j = 0; j < 4; j++)
          acc[i][j] = __builtin_amdgcn_mfma_f32_16x16x32_bf16(bfr[i], af[j], acc[i][j], 0, 0, 0);
    }
#pragma unroll
    for (int t = 0; t < 4; t++) { af[t] = naf[t]; bfr[t] = nbf[t]; }
  }

  const int obase = m0 - qkv_t * CH;  // 0/128/256 within the Q/K/V segment
  if (qkv_t < 2) {
    unsigned short* dst0 = (qkv_t == 0) ? qb : kb;
#pragma unroll
    for (int mt = 0; mt < 4; mt++) {
      const int o = obase + wm + mt * 16 + quad * 4;  // [0,384)
      const int h = o >> 5, d0 = o & 31;
      unsigned short* drow = dst0 + ((size_t)(b * NHEAD + h) * NPIX) * DH + d0;
#pragma unroll
      for (int nt = 0; nt < 4; nt++) {
        const int n = n0 + wn + nt * 16 + cc;
        uint2 p = {pk2(acc[mt][nt][0], acc[mt][nt][1]),
                   pk2(acc[mt][nt][2], acc[mt][nt][3])};
        *(uint2*)(drow + (size_t)n * DH) = p;
      }
    }
  } else {
#pragma unroll
    for (int i = 0; i < 4; i++) {
      const int nbase = n0 + wn + i * 16 + quad * 4;
#pragma unroll
      for (int j = 0; j < 4; j++) {
        const int od = obase + wm + j * 16 + cc;
        const int h = od >> 5, dd = od & 31;
        unsigned short* vrow = vtb + ((size_t)(b * NHEAD + h) * DH + dd) * NPIX;
        *(uint2*)(vrow + nbase) = (uint2){pk2(acc[i][j][0], acc[i][j][1]),
                                          pk2(acc[i][j][2], acc[i][j][3])};
      }
    }
  }
}

// ---------------------------------------------------------------------------
// MFMA attention v9: R3 structure (62.7 us proven) with a REGISTER DIET.
// R10's lb3/lb4 A/B pinned the occupancy ceiling: unified VGPR+AGPR usage
// is just over the 170/wave budget that 3 blocks/CU requires, so (256,3)
// silently falls back to 2 blocks/CU (25% occupancy, every round).  Forcing
// 4 blocks (lb4) spilled (WRITE 6->20 MB, 45 us/half).  The cheapest ~16
// regs: the explicit K-prefetch pair nKa0/nKa1 — R4/R6 proved prefetch
// distance is non-binding, so K is now loaded at the top of its own
// iteration (L2-resident, ~200 cyc exposed, amortized by the extra wave).
// V keeps its natural 1-iteration skew (PV consumes V(t-1)).  Everything
// else verbatim: g=4, KT=32, key-split x2, PSTR=36, LDS P roundtrip,
// ones-MFMA denominator, (256,3), grid (192,8).
// Prediction: occupancy 25 -> ~37%, attn 62.7 -> ~46-54 us.
// Tripwire: WRITE >> 12.3 MB = spill -> revert.
// ---------------------------------------------------------------------------
__global__ __launch_bounds__(256, 3) void attn_mfma(
    const unsigned short* __restrict__ qb, const unsigned short* __restrict__ kb,
    const unsigned short* __restrict__ vtb, unsigned short* __restrict__ ao) {
  constexpr int PSTR = 36;  // 72 B rows: 18c mod 32 hits all 16 even residues
  // 18432 B, shared by Pbuf (during the loop) and the combine buffers (after)
  __shared__ __align__(16) unsigned char smem[18432];
  unsigned short (*Pbuf)[4][16][PSTR] =
      reinterpret_cast<unsigned short(*)[4][16][PSTR]>(smem);  // [4][4][16][36]
  f32x4 (*O0b)[4][64] = reinterpret_cast<f32x4(*)[4][64]>(smem);          // [2][4][64]
  f32x4 (*O1b)[4][64] = reinterpret_cast<f32x4(*)[4][64]>(smem + 8192);   // [2][4][64]
  float (*Lb)[4][64]  = reinterpret_cast<float(*)[4][64]>(smem + 16384);  // [2][4][64]

  const int bh   = blockIdx.x;  // 0..191  (x-major -> XCD = bh % 8)
  const int b    = bh / NHEAD;
  const int h    = bh - b * NHEAD;
  const int tid  = threadIdx.x;
  const int wave = tid >> 6;    // 0..3
  const int lane = tid & 63;
  const int c    = lane & 15;
  const int Q0   = lane >> 4;
  const int w2   = wave & 1;    // query sub-tile
  const int kw   = wave >> 1;   // key half
  const int q0   = blockIdx.y * 128 + w2 * 64;
  const int ks   = kw * 512;

  bf16x8 Bq[4];
#pragma unroll
  for (int g = 0; g < 4; g++)
    Bq[g] = *(const bf16x8*)(qb + ((size_t)bh * NPIX + q0 + 16 * g + c) * DH + Q0 * 8);

  const unsigned short* kbase = kb + (size_t)bh * NPIX * DH;
  const unsigned short* vrow0 = vtb + ((size_t)bh * DH + c) * NPIX;
  const unsigned short* vrow1 = vtb + ((size_t)bh * DH + c + 16) * NPIX;

  const f32x4 zero = {0.f, 0.f, 0.f, 0.f};
  const bf16x8 zero8 = {0, 0, 0, 0, 0, 0, 0, 0};
  const short ONE = (short)0x3F80;  // bf16 1.0
  const bf16x8 ones = {ONE, ONE, ONE, ONE, ONE, ONE, ONE, ONE};

  f32x4 o0[4], o1[4], ls[4];
#pragma unroll
  for (int g = 0; g < 4; g++) { o0[g] = zero; o1[g] = zero; ls[g] = zero; }

  unsigned short* prow[4];
#pragma unroll
  for (int g = 0; g < 4; g++) prow[g] = &Pbuf[wave][g][c][0];

  bf16x8 Vr0 = zero8, Vr1 = zero8;              // V(t-1); PV(-1) adds 0
  bf16x8 Bp[4] = {zero8, zero8, zero8, zero8};  // P(t-1)

#pragma unroll 2
  for (int kt = ks; kt < ks + 512; kt += 32) {
    // K loaded for THIS iteration (no prefetch pair: -16 unified regs);
    // V load is the natural 1-iter skew (consumed by next iter's PV).
    bf16x8 Ka0 = *(const bf16x8*)(kbase + (size_t)(kt + c) * DH + Q0 * 8);
    bf16x8 Ka1 = *(const bf16x8*)(kbase + (size_t)(kt + 16 + c) * DH + Q0 * 8);
    bf16x8 nVa0 = *(const bf16x8*)(vrow0 + kt + Q0 * 8);
    bf16x8 nVa1 = *(const bf16x8*)(vrow1 + kt + Q0 * 8);

    f32x4 s0[4], s1[4];
#pragma unroll
    for (int g = 0; g < 4; g++) {
      s0[g] = __builtin_amdgcn_mfma_f32_16x16x32_bf16(Ka0, Bq[g], zero, 0, 0, 0);
      s1[g] = __builtin_amdgcn_mfma_f32_16x16x32_bf16(Ka1, Bq[g], zero, 0, 0, 0);
    }

#pragma unroll
    for (int g = 0; g < 4; g++) {
      o0[g] = __builtin_amdgcn_mfma_f32_16x16x32_bf16(Vr0, Bp[g], o0[g], 0, 0, 0);
      o1[g] = __builtin_amdgcn_mfma_f32_16x16x32_bf16(Vr1, Bp[g], o1[g], 0, 0, 0);
      ls[g] = __builtin_amdgcn_mfma_f32_16x16x32_bf16(ones, Bp[g], ls[g], 0, 0, 0);
    }

#pragma unroll
    for (int g = 0; g < 4; g++) {
      float p0[4], p1[4];
#pragma unroll
      for (int r = 0; r < 4; r++) p0[r] = EXP2F(s0[g][r]);
#pragma unroll
      for (int r = 0; r < 4; r++) p1[r] = EXP2F(s1[g][r]);
      *(uint2*)(prow[g] + 4 * Q0)      = (uint2){pk2t(p0[0], p0[1]), pk2t(p0[2], p0[3])};
      *(uint2*)(prow[g] + 16 + 4 * Q0) = (uint2){pk2t(p1[0], p1[1]), pk2t(p1[2], p1[3])};
    }
#pragma unroll
    for (int g = 0; g < 4; g++) Bp[g] = *(const bf16x8*)(prow[g] + 8 * Q0);

    Vr0 = nVa0; Vr1 = nVa1;
  }

  // drain the skewed pipe: PV of the last key tile
#pragma unroll
  for (int g = 0; g < 4; g++) {
    o0[g] = __builtin_amdgcn_mfma_f32_16x16x32_bf16(Vr0, Bp[g], o0[g], 0, 0, 0);
    o1[g] = __builtin_amdgcn_mfma_f32_16x16x32_bf16(Vr1, Bp[g], o1[g], 0, 0, 0);
    ls[g] = __builtin_amdgcn_mfma_f32_16x16x32_bf16(ones, Bp[g], ls[g], 0, 0, 0);
  }

  // ---- key-split combine through LDS (Pbuf is dead past this point) ----
  __syncthreads();
  if (kw == 1) {
#pragma unroll
    for (int g = 0; g < 4; g++) {
      O0b[w2][g][lane] = o0[g];
      O1b[w2][g][lane] = o1[g];
      Lb[w2][g][lane]  = ls[g][0];
    }
  }
  __syncthreads();
  if (kw == 1) return;

  // store normalized O in proj's fragment-major layout:
  // row-block rb = (q0>>4)+g, k-chunk = h, row-in-block = c.
#pragma unroll
  for (int g = 0; g < 4; g++) {
    o0[g] += O0b[w2][g][lane];
    o1[g] += O1b[w2][g][lane];
    const float inv = 1.0f / (ls[g][0] + Lb[w2][g][lane]);  // full l[q]
    unsigned short* op = ao +
        (((size_t)b * 64 + (q0 >> 4) + g) * 12 + h) * 512 + c * 8 + 4 * (Q0 & 1);
    *(uint2*)(op + (Q0 >> 1) * 128) =
        (uint2){pk2(o0[g][0] * inv, o0[g][1] * inv),
                pk2(o0[g][2] * inv, o0[g][3] * inv)};
    *(uint2*)(op + (2 + (Q0 >> 1)) * 128) =
        (uint2){pk2(o1[g][0] * inv, o1[g][1] * inv),
                pk2(o1[g][2] * inv, o1[g][3] * inv)};
  }
}

// ---------------------------------------------------------------------------
// Output projection v3: LDS-free, SWIZZLED operands (pw from prep, ao from
// attn).  out[b][c][n] = sum Pw[c,c']*AO[b,n,c'] + bias[c].
// Grid x = b*8+ntile (XCD pin), y = 3 m-tiles; 384 blocks, single pass.
// ---------------------------------------------------------------------------
__global__ __launch_bounds__(256, 3) void proj_mfma(
    const unsigned short* __restrict__ aos, const unsigned short* __restrict__ pws,
    const float* __restrict__ bias, float* __restrict__ out) {
  const int bx = blockIdx.x;
  const int b  = bx >> 3;
  const int n0 = (bx & 7) * 128;
  const int m0 = blockIdx.y * 128;
  const int tid = threadIdx.x, wave = tid >> 6, lane = tid & 63;
  const int wm = (wave >> 1) * 64, wn = (wave & 1) * 64;
  const int cc = lane & 15, quad = lane >> 4;

  const unsigned short* abase =
      pws + ((size_t)((m0 + wm) >> 4) * 12) * 512 + lane * 8;
  const unsigned short* bbase =
      aos + (((size_t)b * 64 + ((n0 + wn) >> 4)) * 12) * 512 + lane * 8;

  f32x4 acc[4][4];
#pragma unroll
  for (int i = 0; i < 4; i++)
#pragma unroll
    for (int j = 0; j < 4; j++) acc[i][j] = (f32x4){0.f, 0.f, 0.f, 0.f};

  bf16x8 af[4], bfr[4];
#pragma unroll
  for (int t = 0; t < 4; t++) af[t] = *(const bf16x8*)(abase + (size_t)(t * 12) * 512);
#pragma unroll
  for (int t = 0; t < 4; t++) bfr[t] = *(const bf16x8*)(bbase + (size_t)(t * 12) * 512);

#pragma unroll 2
  for (int kc = 0; kc < 12; kc++) {
    const int k2 = (kc + 1 < 12) ? kc + 1 : 0;
    bf16x8 naf[4], nbf[4];
#pragma unroll
    for (int t = 0; t < 4; t++)
      naf[t] = *(const bf16x8*)(abase + (size_t)(t * 12 + k2) * 512);
#pragma unroll
    for (int t = 0; t < 4; t++)
      nbf[t] = *(const bf16x8*)(bbase + (size_t)(t * 12 + k2) * 512);
#pragma unroll
    for (int i = 0; i < 4; i++)
#pragma unroll
      for (int j = 0; j < 4; j++)
        acc[i][j] = __builtin_amdgcn_mfma_f32_16x16x32_bf16(af[i], bfr[j], acc[i][j], 0, 0, 0);
#pragma unroll
    for (int t = 0; t < 4; t++) { af[t] = naf[t]; bfr[t] = nbf[t]; }
  }

#pragma unroll
  for (int mt = 0; mt < 4; mt++) {
    const int cbase = m0 + wm + mt * 16 + quad * 4;
    const float4 bi4 = *(const float4*)(bias + cbase);
#pragma unroll
    for (int nt = 0; nt < 4; nt++) {
      const int n = n0 + wn + nt * 16 + cc;
      float* op = out + ((size_t)b * CH + cbase) * NPIX + n;
      op[0 * NPIX] = acc[mt][nt][0] + bi4.x;
      op[1 * NPIX] = acc[mt][nt][1] + bi4.y;
      op[2 * NPIX] = acc[mt][nt][2] + bi4.z;
      op[3 * NPIX] = acc[mt][nt][3] + bi4.w;
    }
  }
}

extern "C" void kernel_launch(void* const* d_in, const int* in_sizes, int n_in,
                              void* d_out, int out_size, void* d_ws, size_t ws_size,
                              hipStream_t stream) {
  const float* x      = (const float*)d_in[0];  // [16,384,32,32]
  const float* qkv_w  = (const float*)d_in[1];  // [1152,384]
  const float* proj_w = (const float*)d_in[2];  // [384,384]
  const float* proj_b = (const float*)d_in[3];  // [384]

  constexpr size_t SEG = (size_t)NB * NPIX * CH;  // 6291456
  unsigned short* ws  = (unsigned short*)d_ws;
  unsigned short* xtw = ws;                         // swizzled
  unsigned short* qbw = ws + SEG;
  unsigned short* kbw = ws + 2 * SEG;
  unsigned short* vtw = ws + 3 * SEG;
  unsigned short* aow = ws + 4 * SEG;               // swizzled
  unsigned short* wqw = ws + 5 * SEG;               // swizzled, 442368
  unsigned short* pww = wqw + (size_t)3 * CH * CH;  // swizzled, 147456

  prep_fused<<<2112, 256, 0, stream>>>(x, qkv_w, proj_w, xtw, wqw, pww);
  // grid x = b*8+ntile: XCD = x%8 pins each xt slice; y = 9 m-tiles
  qkv_mfma<<<dim3(NB * (NPIX / 128), (3 * CH) / 128), 256, 0, stream>>>(xtw, wqw, qbw, kbw, vtw);
  // grid (bh, qtile): same-bh blocks share an XCD -> K/V L2-resident;
  // 4-wave blocks, 128 queries/block, key-split x2, K-prefetch dropped
  attn_mfma<<<dim3(NB * NHEAD, NPIX / 128), 256, 0, stream>>>(qbw, kbw, vtw, aow);
  proj_mfma<<<dim3(NB * (NPIX / 128), CH / 128), 256, 0, stream>>>(aow, pww, proj_b, (float*)d_out);
}

// Round 13
// 181.301 us; speedup vs baseline: 1.0937x; 1.0207x over previous
//
#include <hip/hip_runtime.h>

// Problem constants (fixed by the reference)
constexpr int CH    = 384;    // channels
constexpr int NPIX  = 1024;   // H*W = 32*32
constexpr int NHEAD = 12;
constexpr int DH    = 32;     // head dim
constexpr int NB    = 16;     // batch
constexpr float SCALE = 0.17677669529663689f;  // 32^-0.5
constexpr float LOG2E = 1.4426950408889634f;

typedef __attribute__((ext_vector_type(8))) short bf16x8;  // 8 bf16 (4 VGPRs)
typedef __attribute__((ext_vector_type(4))) float f32x4;   // MFMA C/D frag

// Fragment-major ("swizzled") operand layout for the LDS-free GEMMs:
// a K-major matrix [R][384] is stored as [R/16][12] blocks of 512 bf16;
// within a block, lane (quad*16+cc) holds row cc, k = quad*8..+7 of the
// 32-wide k-chunk, at offset lane*8.  A fragment load is then
// base + lane*8 -> 1 KB fully coalesced per wave instruction.
// elem (r, ch):  off = ((r>>4)*12 + (ch>>5))*512 + (((ch>>3)&3)*16 + (r&15))*8 + (ch&7)

// pack two fp32 -> two bf16, round-half-up (3 VALU)
__device__ __forceinline__ unsigned pk2(float a, float b) {
  return __builtin_amdgcn_perm(__float_as_uint(b) + 0x8000u,
                               __float_as_uint(a) + 0x8000u, 0x07060302u);
}
// pack two fp32 -> two bf16, TRUNCATE (1 VALU) — P only; bias cancels in P/l.
__device__ __forceinline__ unsigned pk2t(float a, float b) {
  return __builtin_amdgcn_perm(__float_as_uint(b), __float_as_uint(a), 0x07060302u);
}

// 2^x on the VALU (v_exp_f32 computes 2^x natively)
#if __has_builtin(__builtin_amdgcn_exp2f)
#define EXP2F(x) __builtin_amdgcn_exp2f(x)
#else
#define EXP2F(x) exp2f(x)
#endif

// ---------------------------------------------------------------------------
// Fused prep: blocks [0,1536) transpose x [b][c][n] fp32 -> xt swizzled bf16
// (per batch: 64 row-blocks x 12 k-chunks); blocks [1536,2112) convert
// weights to swizzled bf16 (Q rows pre-scaled by SCALE*log2e: base-2 logits).
// ---------------------------------------------------------------------------
__global__ __launch_bounds__(256) void prep_fused(
    const float* __restrict__ x, const float* __restrict__ qw,
    const float* __restrict__ pw, unsigned short* __restrict__ xts,
    unsigned short* __restrict__ wqs, unsigned short* __restrict__ pws) {
  const int bx = blockIdx.x;
  const int tid = threadIdx.x;
  if (bx < 1536) {
    __shared__ float T[64][65];
    const int b = bx / 96, rem = bx - b * 96;
    const int c0 = (rem >> 4) * 64, n0 = (rem & 15) * 64;
    const float* xb = x + ((size_t)b * CH + c0) * NPIX + n0;
    const int rn = (tid & 15) * 4, rc = tid >> 4;
#pragma unroll
    for (int i = 0; i < 4; i++) {
      float4 v = *(const float4*)(xb + (size_t)(rc + i * 16) * NPIX + rn);
      T[rc + i * 16][rn + 0] = v.x;
      T[rc + i * 16][rn + 1] = v.y;
      T[rc + i * 16][rn + 2] = v.z;
      T[rc + i * 16][rn + 3] = v.w;
    }
    __syncthreads();
    const int wc = (tid & 15) * 4;  // channel offset within the 64-wide c tile
    const int ch = c0 + wc;         // 4 consecutive channels, j = ch&7 in {0,4}
    const int kc = ch >> 5, qd = (ch >> 3) & 3, j = ch & 7;
#pragma unroll
    for (int i = 0; i < 4; i++) {
      const int nl = (tid >> 4) + i * 16;       // local pixel row
      const int ng = n0 + nl;
      uint2 p = {pk2(T[wc][nl], T[wc + 1][nl]), pk2(T[wc + 2][nl], T[wc + 3][nl])};
      size_t off = (((size_t)b * 64 + (ng >> 4)) * 12 + kc) * 512 +
                   (qd * 16 + (ng & 15)) * 8 + j;
      *(uint2*)(xts + off) = p;
    }
  } else {
    const int idx = (bx - 1536) * 256 + tid;
    if (idx < 110592) {
      float4 v = ((const float4*)qw)[idx];
      const int o  = (idx * 4) / CH;  // 4 | 384: never crosses a row
      const int ch = (idx * 4) - o * CH;
      const float sc = (o < CH) ? SCALE * LOG2E : 1.0f;
      size_t off = (((size_t)(o >> 4)) * 12 + (ch >> 5)) * 512 +
                   (((ch >> 3) & 3) * 16 + (o & 15)) * 8 + (ch & 7);
      *(uint2*)(wqs + off) =
          (uint2){pk2(v.x * sc, v.y * sc), pk2(v.z * sc, v.w * sc)};
    } else {
      const int jdx = idx - 110592;
      float4 v = ((const float4*)pw)[jdx];
      const int o  = (jdx * 4) / CH;
      const int ch = (jdx * 4) - o * CH;
      size_t off = (((size_t)(o >> 4)) * 12 + (ch >> 5)) * 512 +
                   (((ch >> 3) & 3) * 16 + (o & 15)) * 8 + (ch & 7);
      *(uint2*)(pws + off) = (uint2){pk2(v.x, v.y), pk2(v.z, v.w)};
    }
  }
}

// ---------------------------------------------------------------------------
// QKV GEMM v3: LDS-free, SWIZZLED operands.  Y[o, b*1024+n] = Wq.XT^T.
// Every fragment load is base + lane*8 (1 KB coalesced); 1-iter register
// prefetch; no barriers, no LDS, no waitcnt drains.  Grid x = b*8+ntile
// pins each batch's xt slice to one XCD.  V-blocks swap MFMA operands so
// C rows = consecutive pixels -> vectorized d-major stores.
// ---------------------------------------------------------------------------
__global__ __launch_bounds__(256, 3) void qkv_mfma(
    const unsigned short* __restrict__ xts, const unsigned short* __restrict__ wqs,
    unsigned short* __restrict__ qb, unsigned short* __restrict__ kb,
    unsigned short* __restrict__ vtb) {
  const int bx = blockIdx.x;          // b = bx>>3, ntile = bx&7
  const int b  = bx >> 3;
  const int n0 = (bx & 7) * 128;
  const int m0 = blockIdx.y * 128;    // 0..8
  const int qkv_t = blockIdx.y / 3;   // 0=Q, 1=K, 2=V
  const int tid = threadIdx.x, wave = tid >> 6, lane = tid & 63;
  const int wm = (wave >> 1) * 64, wn = (wave & 1) * 64;
  const int cc = lane & 15, quad = lane >> 4;

  const unsigned short* abase =
      wqs + ((size_t)((m0 + wm) >> 4) * 12) * 512 + lane * 8;
  const unsigned short* bbase =
      xts + (((size_t)b * 64 + ((n0 + wn) >> 4)) * 12) * 512 + lane * 8;

  f32x4 acc[4][4];
#pragma unroll
  for (int i = 0; i < 4; i++)
#pragma unroll
    for (int j = 0; j < 4; j++) acc[i][j] = (f32x4){0.f, 0.f, 0.f, 0.f};

  bf16x8 af[4], bfr[4];
#pragma unroll
  for (int t = 0; t < 4; t++) af[t] = *(const bf16x8*)(abase + (size_t)(t * 12) * 512);
#pragma unroll
  for (int t = 0; t < 4; t++) bfr[t] = *(const bf16x8*)(bbase + (size_t)(t * 12) * 512);

#pragma unroll 2
  for (int kc = 0; kc < 12; kc++) {
    const int k2 = (kc + 1 < 12) ? kc + 1 : 0;  // wrap: redundant, in-bounds
    bf16x8 naf[4], nbf[4];
#pragma unroll
    for (int t = 0; t < 4; t++)
      naf[t] = *(const bf16x8*)(abase + (size_t)(t * 12 + k2) * 512);
#pragma unroll
    for (int t = 0; t < 4; t++)
      nbf[t] = *(const bf16x8*)(bbase + (size_t)(t * 12 + k2) * 512);

    if (qkv_t < 2) {
#pragma unroll
      for (int i = 0; i < 4; i++)
#pragma unroll
        for (int j = 0; j < 4; j++)
          acc[i][j] = __builtin_amdgcn_mfma_f32_16x16x32_bf16(af[i], bfr[j], acc[i][j], 0, 0, 0);
    } else {  // V: swap -> C rows = pixels, cols = weight-o
#pragma unroll
      for (int i = 0; i < 4; i++)
#pragma unroll
        for (int j = 0; j < 4; j++)
          acc[i][j] = __builtin_amdgcn_mfma_f32_16x16x32_bf16(bfr[i], af[j], acc[i][j], 0, 0, 0);
    }
#pragma unroll
    for (int t = 0; t < 4; t++) { af[t] = naf[t]; bfr[t] = nbf[t]; }
  }

  const int obase = m0 - qkv_t * CH;  // 0/128/256 within the Q/K/V segment
  if (qkv_t < 2) {
    unsigned short* dst0 = (qkv_t == 0) ? qb : kb;
#pragma unroll
    for (int mt = 0; mt < 4; mt++) {
      const int o = obase + wm + mt * 16 + quad * 4;  // [0,384)
      const int h = o >> 5, d0 = o & 31;
      unsigned short* drow = dst0 + ((size_t)(b * NHEAD + h) * NPIX) * DH + d0;
#pragma unroll
      for (int nt = 0; nt < 4; nt++) {
        const int n = n0 + wn + nt * 16 + cc;
        uint2 p = {pk2(acc[mt][nt][0], acc[mt][nt][1]),
                   pk2(acc[mt][nt][2], acc[mt][nt][3])};
        *(uint2*)(drow + (size_t)n * DH) = p;
      }
    }
  } else {
#pragma unroll
    for (int i = 0; i < 4; i++) {
      const int nbase = n0 + wn + i * 16 + quad * 4;
#pragma unroll
      for (int j = 0; j < 4; j++) {
        const int od = obase + wm + j * 16 + cc;
        const int h = od >> 5, dd = od & 31;
        unsigned short* vrow = vtb + ((size_t)(b * NHEAD + h) * DH + dd) * NPIX;
        *(uint2*)(vrow + nbase) = (uint2){pk2(acc[i][j][0], acc[i][j][1]),
                                          pk2(acc[i][j][2], acc[i][j][3])};
      }
    }
  }
}

// ---------------------------------------------------------------------------
// MFMA attention — EXACT R3 body (62.7 us proven), stamped twice at the
// SAME proven (256,3) config over query halves: _a = queries [0,512),
// _b = [512,1024).  Purpose: attn is plateaued (R1-R11 all failed to beat
// R3; register levers closed by R10/R11), and the other ~113 us of the
// pipeline has NEVER appeared in the top-5 counters (attn at 63 us masks
// everything below it).  Halving the attn dispatch ceiling to ~31 us
// unmasks qkv/prep/proj with full counters at zero risk (byte-identical
// math; R10 already ran this split harmlessly).  Next round targets the
// revealed dominant kernel.
// ---------------------------------------------------------------------------
#define ATTN_BODY(QOFF)                                                        \
  constexpr int PSTR = 36;                                                     \
  __shared__ __align__(16) unsigned char smem[18432];                          \
  unsigned short (*Pbuf)[4][16][PSTR] =                                        \
      reinterpret_cast<unsigned short(*)[4][16][PSTR]>(smem);                  \
  f32x4 (*O0b)[4][64] = reinterpret_cast<f32x4(*)[4][64]>(smem);               \
  f32x4 (*O1b)[4][64] = reinterpret_cast<f32x4(*)[4][64]>(smem + 8192);        \
  float (*Lb)[4][64]  = reinterpret_cast<float(*)[4][64]>(smem + 16384);       \
  const int bh   = blockIdx.x;                                                 \
  const int b    = bh / NHEAD;                                                 \
  const int h    = bh - b * NHEAD;                                             \
  const int tid  = threadIdx.x;                                                \
  const int wave = tid >> 6;                                                   \
  const int lane = tid & 63;                                                   \
  const int c    = lane & 15;                                                  \
  const int Q0   = lane >> 4;                                                  \
  const int w2   = wave & 1;                                                   \
  const int kw   = wave >> 1;                                                  \
  const int q0   = (blockIdx.y + (QOFF)) * 128 + w2 * 64;                      \
  const int ks   = kw * 512;                                                   \
  bf16x8 Bq[4];                                                                \
  _Pragma("unroll")                                                            \
  for (int g = 0; g < 4; g++)                                                  \
    Bq[g] = *(const bf16x8*)(qb + ((size_t)bh * NPIX + q0 + 16 * g + c) * DH + \
                             Q0 * 8);                                          \
  const unsigned short* kbase = kb + (size_t)bh * NPIX * DH;                   \
  const unsigned short* vrow0 = vtb + ((size_t)bh * DH + c) * NPIX;            \
  const unsigned short* vrow1 = vtb + ((size_t)bh * DH + c + 16) * NPIX;       \
  const f32x4 zero = {0.f, 0.f, 0.f, 0.f};                                     \
  const bf16x8 zero8 = {0, 0, 0, 0, 0, 0, 0, 0};                               \
  const short ONE = (short)0x3F80;                                             \
  const bf16x8 ones = {ONE, ONE, ONE, ONE, ONE, ONE, ONE, ONE};                \
  f32x4 o0[4], o1[4], ls[4];                                                   \
  _Pragma("unroll")                                                            \
  for (int g = 0; g < 4; g++) { o0[g] = zero; o1[g] = zero; ls[g] = zero; }    \
  unsigned short* prow[4];                                                     \
  _Pragma("unroll")                                                            \
  for (int g = 0; g < 4; g++) prow[g] = &Pbuf[wave][g][c][0];                  \
  bf16x8 Ka0 = *(const bf16x8*)(kbase + (size_t)(ks + c) * DH + Q0 * 8);       \
  bf16x8 Ka1 = *(const bf16x8*)(kbase + (size_t)(ks + 16 + c) * DH + Q0 * 8);  \
  bf16x8 Vr0 = zero8, Vr1 = zero8;                                             \
  bf16x8 Bp[4] = {zero8, zero8, zero8, zero8};                                 \
  _Pragma("unroll 2")                                                          \
  for (int kt = ks; kt < ks + 512; kt += 32) {                                 \
    const int kt2 = ks + (((kt - ks) + 32) & 511);                             \
    bf16x8 nKa0 = *(const bf16x8*)(kbase + (size_t)(kt2 + c) * DH + Q0 * 8);   \
    bf16x8 nKa1 =                                                              \
        *(const bf16x8*)(kbase + (size_t)(kt2 + 16 + c) * DH + Q0 * 8);        \
    bf16x8 nVa0 = *(const bf16x8*)(vrow0 + kt + Q0 * 8);                       \
    bf16x8 nVa1 = *(const bf16x8*)(vrow1 + kt + Q0 * 8);                       \
    f32x4 s0[4], s1[4];                                                        \
    _Pragma("unroll")                                                          \
    for (int g = 0; g < 4; g++) {                                              \
      s0[g] = __builtin_amdgcn_mfma_f32_16x16x32_bf16(Ka0, Bq[g], zero, 0, 0, 0); \
      s1[g] = __builtin_amdgcn_mfma_f32_16x16x32_bf16(Ka1, Bq[g], zero, 0, 0, 0); \
    }                                                                          \
    _Pragma("unroll")                                                          \
    for (int g = 0; g < 4; g++) {                                              \
      o0[g] = __builtin_amdgcn_mfma_f32_16x16x32_bf16(Vr0, Bp[g], o0[g], 0, 0, 0); \
      o1[g] = __builtin_amdgcn_mfma_f32_16x16x32_bf16(Vr1, Bp[g], o1[g], 0, 0, 0); \
      ls[g] = __builtin_amdgcn_mfma_f32_16x16x32_bf16(ones, Bp[g], ls[g], 0, 0, 0); \
    }                                                                          \
    _Pragma("unroll")                                                          \
    for (int g = 0; g < 4; g++) {                                              \
      float p0[4], p1[4];                                                      \
      _Pragma("unroll")                                                        \
      for (int r = 0; r < 4; r++) p0[r] = EXP2F(s0[g][r]);                     \
      _Pragma("unroll")                                                        \
      for (int r = 0; r < 4; r++) p1[r] = EXP2F(s1[g][r]);                     \
      *(uint2*)(prow[g] + 4 * Q0) =                                            \
          (uint2){pk2t(p0[0], p0[1]), pk2t(p0[2], p0[3])};                     \
      *(uint2*)(prow[g] + 16 + 4 * Q0) =                                       \
          (uint2){pk2t(p1[0], p1[1]), pk2t(p1[2], p1[3])};                     \
    }                                                                          \
    _Pragma("unroll")                                                          \
    for (int g = 0; g < 4; g++) Bp[g] = *(const bf16x8*)(prow[g] + 8 * Q0);    \
    Ka0 = nKa0; Ka1 = nKa1; Vr0 = nVa0; Vr1 = nVa1;                            \
  }                                                                            \
  _Pragma("unroll")                                                            \
  for (int g = 0; g < 4; g++) {                                                \
    o0[g] = __builtin_amdgcn_mfma_f32_16x16x32_bf16(Vr0, Bp[g], o0[g], 0, 0, 0); \
    o1[g] = __builtin_amdgcn_mfma_f32_16x16x32_bf16(Vr1, Bp[g], o1[g], 0, 0, 0); \
    ls[g] = __builtin_amdgcn_mfma_f32_16x16x32_bf16(ones, Bp[g], ls[g], 0, 0, 0); \
  }                                                                            \
  __syncthreads();                                                             \
  if (kw == 1) {                                                               \
    _Pragma("unroll")                                                          \
    for (int g = 0; g < 4; g++) {                                              \
      O0b[w2][g][lane] = o0[g];                                                \
      O1b[w2][g][lane] = o1[g];                                                \
      Lb[w2][g][lane]  = ls[g][0];                                             \
    }                                                                          \
  }                                                                            \
  __syncthreads();                                                             \
  if (kw == 1) return;                                                         \
  _Pragma("unroll")                                                            \
  for (int g = 0; g < 4; g++) {                                                \
    o0[g] += O0b[w2][g][lane];                                                 \
    o1[g] += O1b[w2][g][lane];                                                 \
    const float inv = 1.0f / (ls[g][0] + Lb[w2][g][lane]);                     \
    unsigned short* op = ao +                                                  \
        (((size_t)b * 64 + (q0 >> 4) + g) * 12 + h) * 512 + c * 8 +            \
        4 * (Q0 & 1);                                                          \
    *(uint2*)(op + (Q0 >> 1) * 128) =                                          \
        (uint2){pk2(o0[g][0] * inv, o0[g][1] * inv),                           \
                pk2(o0[g][2] * inv, o0[g][3] * inv)};                          \
    *(uint2*)(op + (2 + (Q0 >> 1)) * 128) =                                    \
        (uint2){pk2(o1[g][0] * inv, o1[g][1] * inv),                           \
                pk2(o1[g][2] * inv, o1[g][3] * inv)};                          \
  }

__global__ __launch_bounds__(256, 3) void attn_mfma_a(
    const unsigned short* __restrict__ qb, const unsigned short* __restrict__ kb,
    const unsigned short* __restrict__ vtb, unsigned short* __restrict__ ao) {
  ATTN_BODY(0)
}

__global__ __launch_bounds__(256, 3) void attn_mfma_b(
    const unsigned short* __restrict__ qb, const unsigned short* __restrict__ kb,
    const unsigned short* __restrict__ vtb, unsigned short* __restrict__ ao) {
  ATTN_BODY(4)
}

// ---------------------------------------------------------------------------
// Output projection v3: LDS-free, SWIZZLED operands (pw from prep, ao from
// attn).  out[b][c][n] = sum Pw[c,c']*AO[b,n,c'] + bias[c].
// Grid x = b*8+ntile (XCD pin), y = 3 m-tiles; 384 blocks, single pass.
// ---------------------------------------------------------------------------
__global__ __launch_bounds__(256, 3) void proj_mfma(
    const unsigned short* __restrict__ aos, const unsigned short* __restrict__ pws,
    const float* __restrict__ bias, float* __restrict__ out) {
  const int bx = blockIdx.x;
  const int b  = bx >> 3;
  const int n0 = (bx & 7) * 128;
  const int m0 = blockIdx.y * 128;
  const int tid = threadIdx.x, wave = tid >> 6, lane = tid & 63;
  const int wm = (wave >> 1) * 64, wn = (wave & 1) * 64;
  const int cc = lane & 15, quad = lane >> 4;

  const unsigned short* abase =
      pws + ((size_t)((m0 + wm) >> 4) * 12) * 512 + lane * 8;
  const unsigned short* bbase =
      aos + (((size_t)b * 64 + ((n0 + wn) >> 4)) * 12) * 512 + lane * 8;

  f32x4 acc[4][4];
#pragma unroll
  for (int i = 0; i < 4; i++)
#pragma unroll
    for (int j = 0; j < 4; j++) acc[i][j] = (f32x4){0.f, 0.f, 0.f, 0.f};

  bf16x8 af[4], bfr[4];
#pragma unroll
  for (int t = 0; t < 4; t++) af[t] = *(const bf16x8*)(abase + (size_t)(t * 12) * 512);
#pragma unroll
  for (int t = 0; t < 4; t++) bfr[t] = *(const bf16x8*)(bbase + (size_t)(t * 12) * 512);

#pragma unroll 2
  for (int kc = 0; kc < 12; kc++) {
    const int k2 = (kc + 1 < 12) ? kc + 1 : 0;
    bf16x8 naf[4], nbf[4];
#pragma unroll
    for (int t = 0; t < 4; t++)
      naf[t] = *(const bf16x8*)(abase + (size_t)(t * 12 + k2) * 512);
#pragma unroll
    for (int t = 0; t < 4; t++)
      nbf[t] = *(const bf16x8*)(bbase + (size_t)(t * 12 + k2) * 512);
#pragma unroll
    for (int i = 0; i < 4; i++)
#pragma unroll
      for (int j = 0; j < 4; j++)
        acc[i][j] = __builtin_amdgcn_mfma_f32_16x16x32_bf16(af[i], bfr[j], acc[i][j], 0, 0, 0);
#pragma unroll
    for (int t = 0; t < 4; t++) { af[t] = naf[t]; bfr[t] = nbf[t]; }
  }

#pragma unroll
  for (int mt = 0; mt < 4; mt++) {
    const int cbase = m0 + wm + mt * 16 + quad * 4;
    const float4 bi4 = *(const float4*)(bias + cbase);
#pragma unroll
    for (int nt = 0; nt < 4; nt++) {
      const int n = n0 + wn + nt * 16 + cc;
      float* op = out + ((size_t)b * CH + cbase) * NPIX + n;
      op[0 * NPIX] = acc[mt][nt][0] + bi4.x;
      op[1 * NPIX] = acc[mt][nt][1] + bi4.y;
      op[2 * NPIX] = acc[mt][nt][2] + bi4.z;
      op[3 * NPIX] = acc[mt][nt][3] + bi4.w;
    }
  }
}

extern "C" void kernel_launch(void* const* d_in, const int* in_sizes, int n_in,
                              void* d_out, int out_size, void* d_ws, size_t ws_size,
                              hipStream_t stream) {
  const float* x      = (const float*)d_in[0];  // [16,384,32,32]
  const float* qkv_w  = (const float*)d_in[1];  // [1152,384]
  const float* proj_w = (const float*)d_in[2];  // [384,384]
  const float* proj_b = (const float*)d_in[3];  // [384]

  constexpr size_t SEG = (size_t)NB * NPIX * CH;  // 6291456
  unsigned short* ws  = (unsigned short*)d_ws;
  unsigned short* xtw = ws;                         // swizzled
  unsigned short* qbw = ws + SEG;
  unsigned short* kbw = ws + 2 * SEG;
  unsigned short* vtw = ws + 3 * SEG;
  unsigned short* aow = ws + 4 * SEG;               // swizzled
  unsigned short* wqw = ws + 5 * SEG;               // swizzled, 442368
  unsigned short* pww = wqw + (size_t)3 * CH * CH;  // swizzled, 147456

  prep_fused<<<2112, 256, 0, stream>>>(x, qkv_w, proj_w, xtw, wqw, pww);
  // grid x = b*8+ntile: XCD = x%8 pins each xt slice; y = 9 m-tiles
  qkv_mfma<<<dim3(NB * (NPIX / 128), (3 * CH) / 128), 256, 0, stream>>>(xtw, wqw, qbw, kbw, vtw);
  // attn = exact R3 math, split into two equal dispatches (queries 0..511
  // and 512..1023) so the sub-63-us kernels surface in the rocprof top-5.
  attn_mfma_a<<<dim3(NB * NHEAD, 4), 256, 0, stream>>>(qbw, kbw, vtw, aow);
  attn_mfma_b<<<dim3(NB * NHEAD, 4), 256, 0, stream>>>(qbw, kbw, vtw, aow);
  proj_mfma<<<dim3(NB * (NPIX / 128), CH / 128), 256, 0, stream>>>(aow, pww, proj_b, (float*)d_out);
}

// Round 14
// 175.200 us; speedup vs baseline: 1.1317x; 1.0348x over previous
//
#include <hip/hip_runtime.h>

// Problem constants (fixed by the reference)
constexpr int CH    = 384;    // channels
constexpr int NPIX  = 1024;   // H*W = 32*32
constexpr int NHEAD = 12;
constexpr int DH    = 32;     // head dim
constexpr int NB    = 16;     // batch
constexpr float SCALE = 0.17677669529663689f;  // 32^-0.5
constexpr float LOG2E = 1.4426950408889634f;

typedef __attribute__((ext_vector_type(8))) short bf16x8;  // 8 bf16 (4 VGPRs)
typedef __attribute__((ext_vector_type(4))) float f32x4;   // MFMA C/D frag

// Fragment-major ("swizzled") operand layout for the LDS-free GEMMs:
// a K-major matrix [R][384] is stored as [R/16][12] blocks of 512 bf16;
// within a block, lane (quad*16+cc) holds row cc, k = quad*8..+7 of the
// 32-wide k-chunk, at offset lane*8.  A fragment load is then
// base + lane*8 -> 1 KB fully coalesced per wave instruction.
// elem (r, ch):  off = ((r>>4)*12 + (ch>>5))*512 + (((ch>>3)&3)*16 + (r&15))*8 + (ch&7)

// pack two fp32 -> two bf16, round-half-up (3 VALU)
__device__ __forceinline__ unsigned pk2(float a, float b) {
  return __builtin_amdgcn_perm(__float_as_uint(b) + 0x8000u,
                               __float_as_uint(a) + 0x8000u, 0x07060302u);
}
// pack two fp32 -> two bf16, TRUNCATE (1 VALU) — P only; bias cancels in P/l.
__device__ __forceinline__ unsigned pk2t(float a, float b) {
  return __builtin_amdgcn_perm(__float_as_uint(b), __float_as_uint(a), 0x07060302u);
}

// 2^x on the VALU (v_exp_f32 computes 2^x natively)
#if __has_builtin(__builtin_amdgcn_exp2f)
#define EXP2F(x) __builtin_amdgcn_exp2f(x)
#else
#define EXP2F(x) exp2f(x)
#endif

// ---------------------------------------------------------------------------
// Fused prep: blocks [0,1536) transpose x [b][c][n] fp32 -> xt swizzled bf16
// (per batch: 64 row-blocks x 12 k-chunks); blocks [1536,2112) convert
// weights to swizzled bf16 (Q rows pre-scaled by SCALE*log2e: base-2 logits).
// ---------------------------------------------------------------------------
__global__ __launch_bounds__(256) void prep_fused(
    const float* __restrict__ x, const float* __restrict__ qw,
    const float* __restrict__ pw, unsigned short* __restrict__ xts,
    unsigned short* __restrict__ wqs, unsigned short* __restrict__ pws) {
  const int bx = blockIdx.x;
  const int tid = threadIdx.x;
  if (bx < 1536) {
    __shared__ float T[64][65];
    const int b = bx / 96, rem = bx - b * 96;
    const int c0 = (rem >> 4) * 64, n0 = (rem & 15) * 64;
    const float* xb = x + ((size_t)b * CH + c0) * NPIX + n0;
    const int rn = (tid & 15) * 4, rc = tid >> 4;
#pragma unroll
    for (int i = 0; i < 4; i++) {
      float4 v = *(const float4*)(xb + (size_t)(rc + i * 16) * NPIX + rn);
      T[rc + i * 16][rn + 0] = v.x;
      T[rc + i * 16][rn + 1] = v.y;
      T[rc + i * 16][rn + 2] = v.z;
      T[rc + i * 16][rn + 3] = v.w;
    }
    __syncthreads();
    const int wc = (tid & 15) * 4;  // channel offset within the 64-wide c tile
    const int ch = c0 + wc;         // 4 consecutive channels, j = ch&7 in {0,4}
    const int kc = ch >> 5, qd = (ch >> 3) & 3, j = ch & 7;
#pragma unroll
    for (int i = 0; i < 4; i++) {
      const int nl = (tid >> 4) + i * 16;       // local pixel row
      const int ng = n0 + nl;
      uint2 p = {pk2(T[wc][nl], T[wc + 1][nl]), pk2(T[wc + 2][nl], T[wc + 3][nl])};
      size_t off = (((size_t)b * 64 + (ng >> 4)) * 12 + kc) * 512 +
                   (qd * 16 + (ng & 15)) * 8 + j;
      *(uint2*)(xts + off) = p;
    }
  } else {
    const int idx = (bx - 1536) * 256 + tid;
    if (idx < 110592) {
      float4 v = ((const float4*)qw)[idx];
      const int o  = (idx * 4) / CH;  // 4 | 384: never crosses a row
      const int ch = (idx * 4) - o * CH;
      const float sc = (o < CH) ? SCALE * LOG2E : 1.0f;
      size_t off = (((size_t)(o >> 4)) * 12 + (ch >> 5)) * 512 +
                   (((ch >> 3) & 3) * 16 + (o & 15)) * 8 + (ch & 7);
      *(uint2*)(wqs + off) =
          (uint2){pk2(v.x * sc, v.y * sc), pk2(v.z * sc, v.w * sc)};
    } else {
      const int jdx = idx - 110592;
      float4 v = ((const float4*)pw)[jdx];
      const int o  = (jdx * 4) / CH;
      const int ch = (jdx * 4) - o * CH;
      size_t off = (((size_t)(o >> 4)) * 12 + (ch >> 5)) * 512 +
                   (((ch >> 3) & 3) * 16 + (o & 15)) * 8 + (ch & 7);
      *(uint2*)(pws + off) = (uint2){pk2(v.x, v.y), pk2(v.z, v.w)};
    }
  }
}

// ---------------------------------------------------------------------------
// QKV GEMM v4: BM=64 tiles (was 128).  R13 diagnosis: prep/qkv/proj are
// latency-bound (~70 us combined vs ~25 us BW floors) and starved of
// blocks in flight.  Halving the M-tile doubles blocks 1152 -> 2304 and
// halves per-block acc registers (64 -> 32), raising resident parallelism;
// total MFMA work unchanged; B-slices stay XCD-pinned L2-resident
// (x-grid unchanged; 128 % 8 == 0 keeps XCD = bx % 8 for all y).
// Per-wave tile is now 32m x 64n: acc flat [8] with STATIC indices
// (Q/K: [i*4+j] i<2 j<4; V swaps operands: [i*2+j] i<4 j<2).
// ---------------------------------------------------------------------------
__global__ __launch_bounds__(256, 3) void qkv_mfma(
    const unsigned short* __restrict__ xts, const unsigned short* __restrict__ wqs,
    unsigned short* __restrict__ qb, unsigned short* __restrict__ kb,
    unsigned short* __restrict__ vtb) {
  const int bx = blockIdx.x;          // b = bx>>3, ntile = bx&7
  const int b  = bx >> 3;
  const int n0 = (bx & 7) * 128;
  const int m0 = blockIdx.y * 64;     // 0..17 -> [0,1152)
  const int qkv_t = blockIdx.y / 6;   // 0=Q, 1=K, 2=V
  const int tid = threadIdx.x, wave = tid >> 6, lane = tid & 63;
  const int wm = (wave >> 1) * 32, wn = (wave & 1) * 64;
  const int cc = lane & 15, quad = lane >> 4;

  const unsigned short* abase =
      wqs + ((size_t)((m0 + wm) >> 4) * 12) * 512 + lane * 8;
  const unsigned short* bbase =
      xts + (((size_t)b * 64 + ((n0 + wn) >> 4)) * 12) * 512 + lane * 8;

  f32x4 acc[8];
#pragma unroll
  for (int t = 0; t < 8; t++) acc[t] = (f32x4){0.f, 0.f, 0.f, 0.f};

  bf16x8 af[2], bfr[4];
#pragma unroll
  for (int t = 0; t < 2; t++) af[t] = *(const bf16x8*)(abase + (size_t)(t * 12) * 512);
#pragma unroll
  for (int t = 0; t < 4; t++) bfr[t] = *(const bf16x8*)(bbase + (size_t)(t * 12) * 512);

#pragma unroll 2
  for (int kc = 0; kc < 12; kc++) {
    const int k2 = (kc + 1 < 12) ? kc + 1 : 0;  // wrap: redundant, in-bounds
    bf16x8 naf[2], nbf[4];
#pragma unroll
    for (int t = 0; t < 2; t++)
      naf[t] = *(const bf16x8*)(abase + (size_t)(t * 12 + k2) * 512);
#pragma unroll
    for (int t = 0; t < 4; t++)
      nbf[t] = *(const bf16x8*)(bbase + (size_t)(t * 12 + k2) * 512);

    if (qkv_t < 2) {
#pragma unroll
      for (int i = 0; i < 2; i++)
#pragma unroll
        for (int j = 0; j < 4; j++)
          acc[i * 4 + j] = __builtin_amdgcn_mfma_f32_16x16x32_bf16(af[i], bfr[j], acc[i * 4 + j], 0, 0, 0);
    } else {  // V: swap -> C rows = pixels, cols = weight-o
#pragma unroll
      for (int i = 0; i < 4; i++)
#pragma unroll
        for (int j = 0; j < 2; j++)
          acc[i * 2 + j] = __builtin_amdgcn_mfma_f32_16x16x32_bf16(bfr[i], af[j], acc[i * 2 + j], 0, 0, 0);
    }
#pragma unroll
    for (int t = 0; t < 2; t++) af[t] = naf[t];
#pragma unroll
    for (int t = 0; t < 4; t++) bfr[t] = nbf[t];
  }

  const int obase = m0 - qkv_t * CH;  // [0,384) within the Q/K/V segment
  if (qkv_t < 2) {
    unsigned short* dst0 = (qkv_t == 0) ? qb : kb;
#pragma unroll
    for (int mt = 0; mt < 2; mt++) {
      const int o = obase + wm + mt * 16 + quad * 4;  // [0,384)
      const int h = o >> 5, d0 = o & 31;
      unsigned short* drow = dst0 + ((size_t)(b * NHEAD + h) * NPIX) * DH + d0;
#pragma unroll
      for (int nt = 0; nt < 4; nt++) {
        const int n = n0 + wn + nt * 16 + cc;
        uint2 p = {pk2(acc[mt * 4 + nt][0], acc[mt * 4 + nt][1]),
                   pk2(acc[mt * 4 + nt][2], acc[mt * 4 + nt][3])};
        *(uint2*)(drow + (size_t)n * DH) = p;
      }
    }
  } else {
#pragma unroll
    for (int i = 0; i < 4; i++) {
      const int nbase = n0 + wn + i * 16 + quad * 4;
#pragma unroll
      for (int j = 0; j < 2; j++) {
        const int od = obase + wm + j * 16 + cc;
        const int h = od >> 5, dd = od & 31;
        unsigned short* vrow = vtb + ((size_t)(b * NHEAD + h) * DH + dd) * NPIX;
        *(uint2*)(vrow + nbase) = (uint2){pk2(acc[i * 2 + j][0], acc[i * 2 + j][1]),
                                          pk2(acc[i * 2 + j][2], acc[i * 2 + j][3])};
      }
    }
  }
}

// ---------------------------------------------------------------------------
// MFMA attention — EXACT R3 body (62.7 us proven), single dispatch again
// (R13 showed the two-way split costs +5.3 us in pure dispatch/tail
// overhead).  64 q/wave, x32 MFMAs, LDS P roundtrip (PSTR=36), key-split
// x2 in a 4-wave block, combine via LDS overlay, (256,3), grid (192,8).
// ---------------------------------------------------------------------------
__global__ __launch_bounds__(256, 3) void attn_mfma(
    const unsigned short* __restrict__ qb, const unsigned short* __restrict__ kb,
    const unsigned short* __restrict__ vtb, unsigned short* __restrict__ ao) {
  constexpr int PSTR = 36;  // 72 B rows: 18c mod 32 hits all 16 even residues
  // 18432 B, shared by Pbuf (during the loop) and the combine buffers (after)
  __shared__ __align__(16) unsigned char smem[18432];
  unsigned short (*Pbuf)[4][16][PSTR] =
      reinterpret_cast<unsigned short(*)[4][16][PSTR]>(smem);  // [4][4][16][36]
  f32x4 (*O0b)[4][64] = reinterpret_cast<f32x4(*)[4][64]>(smem);          // [2][4][64]
  f32x4 (*O1b)[4][64] = reinterpret_cast<f32x4(*)[4][64]>(smem + 8192);   // [2][4][64]
  float (*Lb)[4][64]  = reinterpret_cast<float(*)[4][64]>(smem + 16384);  // [2][4][64]

  const int bh   = blockIdx.x;  // 0..191  (x-major -> XCD = bh % 8)
  const int b    = bh / NHEAD;
  const int h    = bh - b * NHEAD;
  const int tid  = threadIdx.x;
  const int wave = tid >> 6;    // 0..3
  const int lane = tid & 63;
  const int c    = lane & 15;
  const int Q0   = lane >> 4;
  const int w2   = wave & 1;    // query sub-tile
  const int kw   = wave >> 1;   // key half
  const int q0   = blockIdx.y * 128 + w2 * 64;
  const int ks   = kw * 512;

  bf16x8 Bq[4];
#pragma unroll
  for (int g = 0; g < 4; g++)
    Bq[g] = *(const bf16x8*)(qb + ((size_t)bh * NPIX + q0 + 16 * g + c) * DH + Q0 * 8);

  const unsigned short* kbase = kb + (size_t)bh * NPIX * DH;
  const unsigned short* vrow0 = vtb + ((size_t)bh * DH + c) * NPIX;
  const unsigned short* vrow1 = vtb + ((size_t)bh * DH + c + 16) * NPIX;

  const f32x4 zero = {0.f, 0.f, 0.f, 0.f};
  const bf16x8 zero8 = {0, 0, 0, 0, 0, 0, 0, 0};
  const short ONE = (short)0x3F80;  // bf16 1.0
  const bf16x8 ones = {ONE, ONE, ONE, ONE, ONE, ONE, ONE, ONE};

  f32x4 o0[4], o1[4], ls[4];
#pragma unroll
  for (int g = 0; g < 4; g++) { o0[g] = zero; o1[g] = zero; ls[g] = zero; }

  unsigned short* prow[4];
#pragma unroll
  for (int g = 0; g < 4; g++) prow[g] = &Pbuf[wave][g][c][0];

  bf16x8 Ka0 = *(const bf16x8*)(kbase + (size_t)(ks + c) * DH + Q0 * 8);  // K(ks)
  bf16x8 Ka1 = *(const bf16x8*)(kbase + (size_t)(ks + 16 + c) * DH + Q0 * 8);
  bf16x8 Vr0 = zero8, Vr1 = zero8;              // V(t-1); PV(-1) adds 0
  bf16x8 Bp[4] = {zero8, zero8, zero8, zero8};  // P(t-1)

#pragma unroll 2
  for (int kt = ks; kt < ks + 512; kt += 32) {
    const int kt2 = ks + (((kt - ks) + 32) & 511);  // wrap within the half
    bf16x8 nKa0 = *(const bf16x8*)(kbase + (size_t)(kt2 + c) * DH + Q0 * 8);
    bf16x8 nKa1 = *(const bf16x8*)(kbase + (size_t)(kt2 + 16 + c) * DH + Q0 * 8);
    bf16x8 nVa0 = *(const bf16x8*)(vrow0 + kt + Q0 * 8);
    bf16x8 nVa1 = *(const bf16x8*)(vrow1 + kt + Q0 * 8);

    f32x4 s0[4], s1[4];
#pragma unroll
    for (int g = 0; g < 4; g++) {
      s0[g] = __builtin_amdgcn_mfma_f32_16x16x32_bf16(Ka0, Bq[g], zero, 0, 0, 0);
      s1[g] = __builtin_amdgcn_mfma_f32_16x16x32_bf16(Ka1, Bq[g], zero, 0, 0, 0);
    }

#pragma unroll
    for (int g = 0; g < 4; g++) {
      o0[g] = __builtin_amdgcn_mfma_f32_16x16x32_bf16(Vr0, Bp[g], o0[g], 0, 0, 0);
      o1[g] = __builtin_amdgcn_mfma_f32_16x16x32_bf16(Vr1, Bp[g], o1[g], 0, 0, 0);
      ls[g] = __builtin_amdgcn_mfma_f32_16x16x32_bf16(ones, Bp[g], ls[g], 0, 0, 0);
    }

#pragma unroll
    for (int g = 0; g < 4; g++) {
      float p0[4], p1[4];
#pragma unroll
      for (int r = 0; r < 4; r++) p0[r] = EXP2F(s0[g][r]);
#pragma unroll
      for (int r = 0; r < 4; r++) p1[r] = EXP2F(s1[g][r]);
      *(uint2*)(prow[g] + 4 * Q0)      = (uint2){pk2t(p0[0], p0[1]), pk2t(p0[2], p0[3])};
      *(uint2*)(prow[g] + 16 + 4 * Q0) = (uint2){pk2t(p1[0], p1[1]), pk2t(p1[2], p1[3])};
    }
#pragma unroll
    for (int g = 0; g < 4; g++) Bp[g] = *(const bf16x8*)(prow[g] + 8 * Q0);

    Ka0 = nKa0; Ka1 = nKa1; Vr0 = nVa0; Vr1 = nVa1;
  }

#pragma unroll
  for (int g = 0; g < 4; g++) {
    o0[g] = __builtin_amdgcn_mfma_f32_16x16x32_bf16(Vr0, Bp[g], o0[g], 0, 0, 0);
    o1[g] = __builtin_amdgcn_mfma_f32_16x16x32_bf16(Vr1, Bp[g], o1[g], 0, 0, 0);
    ls[g] = __builtin_amdgcn_mfma_f32_16x16x32_bf16(ones, Bp[g], ls[g], 0, 0, 0);
  }

  // ---- key-split combine through LDS (Pbuf is dead past this point) ----
  __syncthreads();
  if (kw == 1) {
#pragma unroll
    for (int g = 0; g < 4; g++) {
      O0b[w2][g][lane] = o0[g];
      O1b[w2][g][lane] = o1[g];
      Lb[w2][g][lane]  = ls[g][0];
    }
  }
  __syncthreads();
  if (kw == 1) return;

  // store normalized O in proj's fragment-major layout:
  // row-block rb = (q0>>4)+g, k-chunk = h, row-in-block = c.
#pragma unroll
  for (int g = 0; g < 4; g++) {
    o0[g] += O0b[w2][g][lane];
    o1[g] += O1b[w2][g][lane];
    const float inv = 1.0f / (ls[g][0] + Lb[w2][g][lane]);  // full l[q]
    unsigned short* op = ao +
        (((size_t)b * 64 + (q0 >> 4) + g) * 12 + h) * 512 + c * 8 + 4 * (Q0 & 1);
    *(uint2*)(op + (Q0 >> 1) * 128) =
        (uint2){pk2(o0[g][0] * inv, o0[g][1] * inv),
                pk2(o0[g][2] * inv, o0[g][3] * inv)};
    *(uint2*)(op + (2 + (Q0 >> 1)) * 128) =
        (uint2){pk2(o1[g][0] * inv, o1[g][1] * inv),
                pk2(o1[g][2] * inv, o1[g][3] * inv)};
  }
}

// ---------------------------------------------------------------------------
// Output projection v4: BM=64 tiles (was 128).  Same rationale as qkv v4:
// proj previously launched only 384 blocks (1.5/CU available — half the
// machine idle on a latency-bound kernel).  Now 768 blocks (exactly 3/CU),
// acc 32 regs, per-wave tile 32m x 64n.  XCD pinning unchanged.
// ---------------------------------------------------------------------------
__global__ __launch_bounds__(256, 3) void proj_mfma(
    const unsigned short* __restrict__ aos, const unsigned short* __restrict__ pws,
    const float* __restrict__ bias, float* __restrict__ out) {
  const int bx = blockIdx.x;
  const int b  = bx >> 3;
  const int n0 = (bx & 7) * 128;
  const int m0 = blockIdx.y * 64;   // 0..5
  const int tid = threadIdx.x, wave = tid >> 6, lane = tid & 63;
  const int wm = (wave >> 1) * 32, wn = (wave & 1) * 64;
  const int cc = lane & 15, quad = lane >> 4;

  const unsigned short* abase =
      pws + ((size_t)((m0 + wm) >> 4) * 12) * 512 + lane * 8;
  const unsigned short* bbase =
      aos + (((size_t)b * 64 + ((n0 + wn) >> 4)) * 12) * 512 + lane * 8;

  f32x4 acc[2][4];
#pragma unroll
  for (int i = 0; i < 2; i++)
#pragma unroll
    for (int j = 0; j < 4; j++) acc[i][j] = (f32x4){0.f, 0.f, 0.f, 0.f};

  bf16x8 af[2], bfr[4];
#pragma unroll
  for (int t = 0; t < 2; t++) af[t] = *(const bf16x8*)(abase + (size_t)(t * 12) * 512);
#pragma unroll
  for (int t = 0; t < 4; t++) bfr[t] = *(const bf16x8*)(bbase + (size_t)(t * 12) * 512);

#pragma unroll 2
  for (int kc = 0; kc < 12; kc++) {
    const int k2 = (kc + 1 < 12) ? kc + 1 : 0;
    bf16x8 naf[2], nbf[4];
#pragma unroll
    for (int t = 0; t < 2; t++)
      naf[t] = *(const bf16x8*)(abase + (size_t)(t * 12 + k2) * 512);
#pragma unroll
    for (int t = 0; t < 4; t++)
      nbf[t] = *(const bf16x8*)(bbase + (size_t)(t * 12 + k2) * 512);
#pragma unroll
    for (int i = 0; i < 2; i++)
#pragma unroll
      for (int j = 0; j < 4; j++)
        acc[i][j] = __builtin_amdgcn_mfma_f32_16x16x32_bf16(af[i], bfr[j], acc[i][j], 0, 0, 0);
#pragma unroll
    for (int t = 0; t < 2; t++) af[t] = naf[t];
#pragma unroll
    for (int t = 0; t < 4; t++) bfr[t] = nbf[t];
  }

#pragma unroll
  for (int mt = 0; mt < 2; mt++) {
    const int cbase = m0 + wm + mt * 16 + quad * 4;
    const float4 bi4 = *(const float4*)(bias + cbase);
#pragma unroll
    for (int nt = 0; nt < 4; nt++) {
      const int n = n0 + wn + nt * 16 + cc;
      float* op = out + ((size_t)b * CH + cbase) * NPIX + n;
      op[0 * NPIX] = acc[mt][nt][0] + bi4.x;
      op[1 * NPIX] = acc[mt][nt][1] + bi4.y;
      op[2 * NPIX] = acc[mt][nt][2] + bi4.z;
      op[3 * NPIX] = acc[mt][nt][3] + bi4.w;
    }
  }
}

extern "C" void kernel_launch(void* const* d_in, const int* in_sizes, int n_in,
                              void* d_out, int out_size, void* d_ws, size_t ws_size,
                              hipStream_t stream) {
  const float* x      = (const float*)d_in[0];  // [16,384,32,32]
  const float* qkv_w  = (const float*)d_in[1];  // [1152,384]
  const float* proj_w = (const float*)d_in[2];  // [384,384]
  const float* proj_b = (const float*)d_in[3];  // [384]

  constexpr size_t SEG = (size_t)NB * NPIX * CH;  // 6291456
  unsigned short* ws  = (unsigned short*)d_ws;
  unsigned short* xtw = ws;                         // swizzled
  unsigned short* qbw = ws + SEG;
  unsigned short* kbw = ws + 2 * SEG;
  unsigned short* vtw = ws + 3 * SEG;
  unsigned short* aow = ws + 4 * SEG;               // swizzled
  unsigned short* wqw = ws + 5 * SEG;               // swizzled, 442368
  unsigned short* pww = wqw + (size_t)3 * CH * CH;  // swizzled, 147456

  prep_fused<<<2112, 256, 0, stream>>>(x, qkv_w, proj_w, xtw, wqw, pww);
  // grid x = b*8+ntile: XCD = x%8 pins each xt slice; y = 18 BM=64 m-tiles
  qkv_mfma<<<dim3(NB * (NPIX / 128), (3 * CH) / 64), 256, 0, stream>>>(xtw, wqw, qbw, kbw, vtw);
  // single attn dispatch (R3 exact) — the R13 split cost +5.3 us overhead
  attn_mfma<<<dim3(NB * NHEAD, NPIX / 128), 256, 0, stream>>>(qbw, kbw, vtw, aow);
  // proj: 768 blocks (BM=64) = exactly 3 blocks/CU
  proj_mfma<<<dim3(NB * (NPIX / 128), CH / 64), 256, 0, stream>>>(aow, pww, proj_b, (float*)d_out);
}